// Round 12
// baseline (202.174 us; speedup 1.0000x reference)
//
#include <hip/hip_runtime.h>
#include <hip/hip_bf16.h>
#include <math.h>

typedef unsigned short u16;
typedef unsigned int u32;
typedef __attribute__((ext_vector_type(4))) float f32x4;
typedef __attribute__((ext_vector_type(8))) short bf16x8;
typedef __attribute__((ext_vector_type(4))) unsigned short us4;
typedef __attribute__((ext_vector_type(8))) unsigned short us8;

#define DI __device__ __forceinline__

// natural -1e9 scaled by log2(e): softmax computed in base-2 domain
#define NEGS  (-1.4426950408889634e9f)
#define QKSCL (0.18033688011112042f)     // 0.125 * log2(e)
#define DEFTH (11.541560327111708f)      // 8 * log2(e)

DI u16 f2b(float x){ __hip_bfloat16 h = __float2bfloat16(x); return *reinterpret_cast<u16*>(&h); }
DI float b2f(u16 u){ union { float f; u32 i; } v; v.i = ((u32)u) << 16; return v.f; }

DI u32 cvtpk(float lo, float hi){
  u32 r;
  asm("v_cvt_pk_bf16_f32 %0, %1, %2" : "=v"(r) : "v"(lo), "v"(hi));
  return r;
}
DI float exp2a(float x){
  float r;
  asm("v_exp_f32 %0, %1" : "=v"(r) : "v"(x));
  return r;
}

// direct global->LDS DMA, 16B per lane; LDS dest = wave-uniform base + lane*16
DI void gload16(const void* g, void* l){
  __builtin_amdgcn_global_load_lds((const __attribute__((address_space(1))) void*)g,
                                   (__attribute__((address_space(3))) void*)l, 16, 0, 0);
}

// ------------------------------------------------------------------
// 1+2 merged) k_prep: blocks [0,1024) weights->bf16; [1024,2048) pooled
// ------------------------------------------------------------------
__global__ __launch_bounds__(256) void k_prep(const float* __restrict__ Wq, const float* __restrict__ Wk,
    const float* __restrict__ Wv, const float* __restrict__ Wo,
    u16* __restrict__ WB, u16* __restrict__ WoB,
    const float* __restrict__ x, float* __restrict__ pooled){
  if (blockIdx.x < 1024){
    int i = blockIdx.x * 256 + threadIdx.x;
    WB[i]          = f2b(Wq[i]);
    WB[262144 + i] = f2b(Wk[i]);
    WB[524288 + i] = f2b(Wv[i]);
    WoB[i]         = f2b(Wo[i]);
  } else {
    int row  = (blockIdx.x - 1024) * 4 + (threadIdx.x >> 6);
    int lane = threadIdx.x & 63;
    const float4* p = (const float4*)(x + ((size_t)row << 10));
    float4 v0 = p[lane], v1 = p[lane + 64], v2 = p[lane + 128], v3 = p[lane + 192];
    float s = (v0.x + v0.y + v0.z + v0.w) + (v1.x + v1.y + v1.z + v1.w)
            + (v2.x + v2.y + v2.z + v2.w) + (v3.x + v3.y + v3.z + v3.w);
    #pragma unroll
    for (int o = 32; o > 0; o >>= 1) s += __shfl_down(s, o, 64);
    if (lane == 0) pooled[row] = s * (1.0f / 1024.0f);
  }
}

// ------------------------------------------------------------------
// 3) SE
// ------------------------------------------------------------------
__global__ __launch_bounds__(256) void k_se(const float* __restrict__ pooled,
    const float* __restrict__ Wse1, const float* __restrict__ bse1,
    const float* __restrict__ Wse2, const float* __restrict__ bse2,
    float* __restrict__ cw){
  __shared__ float pl[512];
  __shared__ float h1[32];
  int b = blockIdx.x, t = threadIdx.x;
  pl[t] = pooled[b * 512 + t];
  pl[t + 256] = pooled[b * 512 + t + 256];
  __syncthreads();
  if (t < 32){
    float acc = bse1[t];
    const float* w = Wse1 + t * 512;
    for (int c = 0; c < 512; c++) acc = fmaf(pl[c], w[c], acc);
    h1[t] = fmaxf(acc, 0.0f);
  }
  __syncthreads();
  for (int c = t; c < 512; c += 256){
    float acc = bse2[c];
    const float* w = Wse2 + c * 32;
    #pragma unroll
    for (int j = 0; j < 32; j++) acc = fmaf(h1[j], w[j], acc);
    cw[b * 512 + c] = 1.0f / (1.0f + expf(-acc));
  }
}

// ------------------------------------------------------------------
// 4+6 fused) k_spxf: one pass over x producing mbuf (f32) + xfB (bf16^T)
// ------------------------------------------------------------------
__global__ __launch_bounds__(256) void k_spxf(const float* __restrict__ x,
    const float* __restrict__ Wsp, const float* __restrict__ bsp,
    const float* __restrict__ cw, float* __restrict__ mbuf, u16* __restrict__ xfB){
  __shared__ float wsh[4096];
  __shared__ float cwl[512];
  __shared__ float tile[64][36];
  __shared__ float part[8][256];
  int t = threadIdx.x;
  int b = blockIdx.x >> 5, n0 = (blockIdx.x & 31) << 5;
  for (int i = t; i < 4096; i += 256) wsh[i] = Wsp[i];
  cwl[t] = cw[b * 512 + t];
  cwl[t + 256] = cw[b * 512 + t + 256];

  int nl = t & 31, cg = t >> 5;
  int lr = t >> 2, lc = (t & 3) << 3;
  float acc[8] = {0,0,0,0,0,0,0,0};

  for (int cb = 0; cb < 8; cb++){
    __syncthreads();
    const float* xp = x + ((size_t)(b * 512 + cb * 64 + lr) << 10) + n0 + lc;
    float4 v0 = *(const float4*)xp;
    float4 v1 = *(const float4*)(xp + 4);
    *(float4*)&tile[lr][lc]     = v0;
    *(float4*)&tile[lr][lc + 4] = v1;
    __syncthreads();
    float sc[8];
    #pragma unroll
    for (int i = 0; i < 8; i++){
      int c = cb * 64 + cg * 8 + i;
      float v = tile[cg * 8 + i][nl];
      sc[i] = v * cwl[c];
      #pragma unroll
      for (int h = 0; h < 8; h++) acc[h] = fmaf(v, wsh[(h << 9) + c], acc[h]);
    }
    union { u32 d[4]; us8 v; } xu;
    #pragma unroll
    for (int i = 0; i < 4; i++) xu.d[i] = cvtpk(sc[2*i], sc[2*i+1]);
    *(us8*)&xfB[(((size_t)(b * 1024 + n0 + nl)) << 9) + cb * 64 + cg * 8] = xu.v;
  }
  #pragma unroll
  for (int h = 0; h < 8; h++) part[cg][h * 32 + nl] = acc[h];
  __syncthreads();
  {
    int h = t >> 5, px = t & 31;
    float s = bsp[h];
    #pragma unroll
    for (int g2 = 0; g2 < 8; g2++) s += part[g2][h * 32 + px];
    mbuf[(((size_t)(b * 8 + h)) << 10) + n0 + px] = 1.0f / (1.0f + expf(-s));
  }
}

// ------------------------------------------------------------------
// 5) adaptive pool 7x7, threshold, upsample -> bneg (B,8,N) in {0, NEGS}
// ------------------------------------------------------------------
__global__ void k_mask(const float* __restrict__ mbuf, float* __restrict__ bneg){
  __shared__ float sm[1024];
  __shared__ float mg[49];
  int bh = blockIdx.x, t = threadIdx.x;
  const float* mp = mbuf + ((size_t)bh << 10);
  for (int i = t; i < 1024; i += 64) sm[i] = mp[i];
  __syncthreads();
  if (t < 49){
    int ci = t / 7, cj = t % 7;
    int r0 = (ci * 32) / 7, r1 = ((ci + 1) * 32 + 6) / 7;
    int c0 = (cj * 32) / 7, c1 = ((cj + 1) * 32 + 6) / 7;
    float acc = 0.0f;
    for (int cc = c0; cc < c1; cc++){
      float rs = 0.0f;
      for (int rr = r0; rr < r1; rr++) rs += sm[rr * 32 + cc];
      acc += rs / (float)(r1 - r0);
    }
    float v = acc / (float)(c1 - c0);
    mg[t] = (v > 0.5f) ? 1.0f : 0.0f;
  }
  __syncthreads();
  for (int i = t; i < 1024; i += 64){
    int r = i >> 5, c = i & 31;
    float m = mg[((r * 7) >> 5) * 7 + ((c * 7) >> 5)];
    bneg[((size_t)bh << 10) + i] = (m > 0.5f) ? 0.0f : NEGS;
  }
}

// ------------------------------------------------------------------
// 7/9) bf16 MFMA GEMM — dbuf global_load_lds(16B), BK=32, one barrier/step.
//   __launch_bounds__(256,4): cap 128 VGPR -> 4 blocks/CU (was 3 @132).
// ------------------------------------------------------------------
template<int MODE>
DI void gemm_body(const u16* __restrict__ A, const u16* __restrict__ Bw,
    const float* __restrict__ b0, const float* __restrict__ b1, const float* __restrict__ b2,
    u16* __restrict__ outQ, u16* __restrict__ outK, u16* __restrict__ outV, u16* __restrict__ outO){
  __shared__ __align__(16) u16 smem[16384];
  int m0 = blockIdx.x * 128, n0 = blockIdx.y * 128;
  bool vblk = (MODE == 0) && (n0 >= 1024);
  int t = threadIdx.x, lane = t & 63, w = t >> 6;
  int wr = w >> 1, wc = w & 1;
  int g = lane >> 4, li = lane & 15;
  f32x4 acc[4][4];
  #pragma unroll
  for (int mt = 0; mt < 4; mt++)
    #pragma unroll
    for (int nt = 0; nt < 4; nt++) acc[mt][nt] = (f32x4){0.f, 0.f, 0.f, 0.f};

  int cof = (((lane & 3) ^ ((lane >> 3) & 3)) << 3);
  int rl = lane >> 2;
  const u16* gA = A  + (size_t)(m0 + w * 32 + rl) * 512 + cof;
  const u16* gB = Bw + (size_t)(n0 + w * 32 + rl) * 512 + cof;
  u16* lA = smem + (w * 32) * 32;
  u16* lB = smem + 4096 + (w * 32) * 32;

  #define STAGE(buf, k0)                                              \
    gload16(gA + (k0),            lA + (buf) * 8192);                 \
    gload16(gA + (k0) + 16 * 512, lA + (buf) * 8192 + 512);           \
    gload16(gB + (k0),            lB + (buf) * 8192);                 \
    gload16(gB + (k0) + 16 * 512, lB + (buf) * 8192 + 512);

  STAGE(0, 0);
  __syncthreads();

  int rsw = ((li >> 1) & 3);
  int cA = (g ^ rsw) << 3;
  int cur = 0;
  for (int ks = 0; ks < 16; ks++){
    if (ks < 15){ STAGE(cur ^ 1, (ks + 1) * 32); }
    const u16* Ac = smem + cur * 8192;
    const u16* Bc = smem + cur * 8192 + 4096;
    bf16x8 afr[4], bfr[4];
    #pragma unroll
    for (int mt = 0; mt < 4; mt++)
      afr[mt] = *(const bf16x8*)&Ac[(wr * 64 + mt * 16 + li) * 32 + cA];
    #pragma unroll
    for (int nt = 0; nt < 4; nt++)
      bfr[nt] = *(const bf16x8*)&Bc[(wc * 64 + nt * 16 + li) * 32 + cA];
    if (vblk){
      #pragma unroll
      for (int mt = 0; mt < 4; mt++)
        #pragma unroll
        for (int nt = 0; nt < 4; nt++)
          acc[mt][nt] = __builtin_amdgcn_mfma_f32_16x16x32_bf16(afr[mt], bfr[nt], acc[mt][nt], 0, 0, 0);
    } else {
      #pragma unroll
      for (int mt = 0; mt < 4; mt++)
        #pragma unroll
        for (int nt = 0; nt < 4; nt++)
          acc[mt][nt] = __builtin_amdgcn_mfma_f32_16x16x32_bf16(bfr[nt], afr[mt], acc[mt][nt], 0, 0, 0);
    }
    __syncthreads();
    cur ^= 1;
  }
  #undef STAGE

  // ---- two-pass LDS-staged coalesced epilogue
  u16* Cl = smem;   // 64 x 136
  const float* bb = vblk ? b2 : ((MODE == 0 && (n0 >> 9)) ? b1 : b0);
  #pragma unroll
  for (int p = 0; p < 2; p++){
    __syncthreads();
    if (vblk){
      if (wc == p){
        #pragma unroll
        for (int mt = 0; mt < 4; mt++){
          #pragma unroll
          for (int nt = 0; nt < 4; nt++){
            int row = nt * 16 + li;
            float bias = bb[(n0 & 511) + p * 64 + row];
            int col = wr * 64 + ((mt >> 1) << 5) + (g << 3) + ((mt & 1) << 2);
            union { u32 d[2]; us4 v; } pu;
            pu.d[0] = cvtpk(acc[mt][nt][0] + bias, acc[mt][nt][1] + bias);
            pu.d[1] = cvtpk(acc[mt][nt][2] + bias, acc[mt][nt][3] + bias);
            *(us4*)&Cl[row * 136 + col] = pu.v;
          }
        }
      }
    } else {
      if (wr == p){
        #pragma unroll
        for (int mt = 0; mt < 4; mt++){
          #pragma unroll
          for (int nt = 0; nt < 4; nt++){
            int row = mt * 16 + li;
            int ob = wc * 64 + nt * 16 + (g << 2);
            float4 bias4 = *(const float4*)&bb[(n0 & 511) + ob];
            union { u32 d[2]; us4 v; } pu;
            pu.d[0] = cvtpk(acc[mt][nt][0] + bias4.x, acc[mt][nt][1] + bias4.y);
            pu.d[1] = cvtpk(acc[mt][nt][2] + bias4.z, acc[mt][nt][3] + bias4.w);
            *(us4*)&Cl[row * 136 + ob] = pu.v;
          }
        }
      }
    }
    __syncthreads();
    int r = t >> 4, ol = (t & 15) << 3;
    if (vblk){
      int b = m0 >> 10, nt0 = m0 & 1023;
      #pragma unroll
      for (int pp = 0; pp < 4; pp++){
        int rr = pp * 16 + r;
        int c = (n0 & 511) + p * 64 + rr, h = c >> 6, dv = c & 63;
        us8 v = *(us8*)&Cl[rr * 136 + ol];
        *(us8*)&outV[(((size_t)(b * 8 + h)) << 16) + ((size_t)dv << 10) + nt0 + ol] = v;
      }
    } else if (MODE == 0){
      u16* base = (n0 >> 9) ? outK : outQ;
      #pragma unroll
      for (int pp = 0; pp < 4; pp++){
        int rr = pp * 16 + r;
        int m = m0 + p * 64 + rr, b = m >> 10, n = m & 1023;
        int c = (n0 & 511) + ol, h = c >> 6, dv = c & 63;
        us8 v = *(us8*)&Cl[rr * 136 + ol];
        *(us8*)&base[(((size_t)(b * 8 + h)) << 16) + ((size_t)n << 6) + dv] = v;
      }
    } else {
      #pragma unroll
      for (int pp = 0; pp < 4; pp++){
        int rr = pp * 16 + r;
        int m = m0 + p * 64 + rr;
        us8 v = *(us8*)&Cl[rr * 136 + ol];
        *(us8*)&outO[((size_t)m << 9) + n0 + ol] = v;
      }
    }
  }
}

__global__ __launch_bounds__(256, 4) void k_gemm_qkv(const u16* __restrict__ A, const u16* __restrict__ Bw,
    const float* __restrict__ b0, const float* __restrict__ b1, const float* __restrict__ b2,
    u16* __restrict__ outQ, u16* __restrict__ outK, u16* __restrict__ outV){
  gemm_body<0>(A, Bw, b0, b1, b2, outQ, outK, outV, nullptr);
}

__global__ __launch_bounds__(256, 4) void k_gemm_o(const u16* __restrict__ A, const u16* __restrict__ Bw,
    const float* __restrict__ b0, u16* __restrict__ outO){
  gemm_body<1>(A, Bw, b0, nullptr, nullptr, nullptr, nullptr, nullptr, outO);
}

// ------------------------------------------------------------------
// 8) flash attention: 32 q-rows/wave, pitch-88 LDS, dbuf, base-2 softmax,
//    cvt_pk, defer-max, XCD swizzle, setprio. (proven r11 structure)
// ------------------------------------------------------------------
__global__ __launch_bounds__(256) void k_flash(const u16* __restrict__ Q, const u16* __restrict__ K,
    const u16* __restrict__ Vt, const float* __restrict__ bneg, u16* __restrict__ attnB){
  __shared__ __align__(16) u16 Ks[2][64 * 88];
  __shared__ __align__(16) u16 Vts[2][64 * 88];
  __shared__ float mks[2][64];
  int hw = blockIdx.x;
  int bid = ((hw & 7) << 6) + (hw >> 3);
  int bh = bid >> 3, q0 = (bid & 7) << 7;
  int t = threadIdx.x, lane = t & 63, w = t >> 6;
  int g = lane >> 4, li = lane & 15;

  const u16* Kp = K  + ((size_t)bh << 16);
  const u16* Vp = Vt + ((size_t)bh << 16);
  const float* bp = bneg + ((size_t)bh << 10);

  bf16x8 qf0a, qf1a, qf0b, qf1b;
  {
    const u16* qra = Q + ((size_t)bh << 16) + ((size_t)(q0 + w * 32 + li) << 6);
    qf0a = *(const bf16x8*)(qra + g * 8);
    qf1a = *(const bf16x8*)(qra + 32 + g * 8);
    const u16* qrb = qra + (16 << 6);
    qf0b = *(const bf16x8*)(qrb + g * 8);
    qf1b = *(const bf16x8*)(qrb + 32 + g * 8);
  }
  float bnqa = bp[q0 + w * 32 + li];
  float bnqb = bp[q0 + w * 32 + 16 + li];

  f32x4 oaccA[4], oaccB[4];
  #pragma unroll
  for (int dt = 0; dt < 4; dt++){
    oaccA[dt] = (f32x4){0.f, 0.f, 0.f, 0.f};
    oaccB[dt] = (f32x4){0.f, 0.f, 0.f, 0.f};
  }
  float mrunA = -INFINITY, lrunA = 0.0f, mrunB = -INFINITY, lrunB = 0.0f;

  int sr = t >> 2, sc = (t & 3) << 4;
  const u16* kg = Kp + ((size_t)sr << 6) + sc;
  const u16* vg = Vp + ((size_t)sr << 10) + sc;
  uint4 kr0 = *(const uint4*)(kg), kr1 = *(const uint4*)(kg + 8);
  uint4 vr0 = *(const uint4*)(vg), vr1 = *(const uint4*)(vg + 8);
  float mr = (t < 64) ? bp[t] : 0.0f;

  *(uint4*)&Ks[0][sr * 88 + sc]      = kr0;
  *(uint4*)&Ks[0][sr * 88 + sc + 8]  = kr1;
  *(uint4*)&Vts[0][sr * 88 + sc]     = vr0;
  *(uint4*)&Vts[0][sr * 88 + sc + 8] = vr1;
  if (t < 64) mks[0][t] = mr;
  __syncthreads();

  for (int kt = 0; kt < 16; kt++){
    int buf = kt & 1;
    if (kt < 15){
      kr0 = *(const uint4*)(kg + (kt + 1) * 4096);
      kr1 = *(const uint4*)(kg + (kt + 1) * 4096 + 8);
      vr0 = *(const uint4*)(vg + (kt + 1) * 64);
      vr1 = *(const uint4*)(vg + (kt + 1) * 64 + 8);
      if (t < 64) mr = bp[(kt + 1) * 64 + t];
    }

    f32x4 sa[4], sb[4];
    #pragma unroll
    for (int mt = 0; mt < 4; mt++){ sa[mt] = (f32x4){0.f,0.f,0.f,0.f}; sb[mt] = (f32x4){0.f,0.f,0.f,0.f}; }
    __builtin_amdgcn_s_setprio(1);
    #pragma unroll
    for (int mt = 0; mt < 4; mt++){
      bf16x8 kf0 = *(bf16x8*)&Ks[buf][(mt * 16 + li) * 88 + g * 8];
      bf16x8 kf1 = *(bf16x8*)&Ks[buf][(mt * 16 + li) * 88 + 32 + g * 8];
      sa[mt] = __builtin_amdgcn_mfma_f32_16x16x32_bf16(kf0, qf0a, sa[mt], 0, 0, 0);
      sa[mt] = __builtin_amdgcn_mfma_f32_16x16x32_bf16(kf1, qf1a, sa[mt], 0, 0, 0);
      sb[mt] = __builtin_amdgcn_mfma_f32_16x16x32_bf16(kf0, qf0b, sb[mt], 0, 0, 0);
      sb[mt] = __builtin_amdgcn_mfma_f32_16x16x32_bf16(kf1, qf1b, sb[mt], 0, 0, 0);
    }
    __builtin_amdgcn_s_setprio(0);

    union { u32 d[4]; bf16x8 v; } u0a, u1a, u0b, u1b;
    {
      float tm[4];
      #pragma unroll
      for (int mt = 0; mt < 4; mt++){
        float4 bk = *(const float4*)&mks[buf][mt * 16 + g * 4];
        float s0 = fmaf(sa[mt][0], QKSCL, fminf(bk.x, bnqa));
        float s1 = fmaf(sa[mt][1], QKSCL, fminf(bk.y, bnqa));
        float s2 = fmaf(sa[mt][2], QKSCL, fminf(bk.z, bnqa));
        float s3 = fmaf(sa[mt][3], QKSCL, fminf(bk.w, bnqa));
        sa[mt][0] = s0; sa[mt][1] = s1; sa[mt][2] = s2; sa[mt][3] = s3;
        tm[mt] = fmaxf(fmaxf(s0, s1), fmaxf(s2, s3));
      }
      float tmax = fmaxf(fmaxf(tm[0], tm[1]), fmaxf(tm[2], tm[3]));
      tmax = fmaxf(tmax, __shfl_xor(tmax, 16, 64));
      tmax = fmaxf(tmax, __shfl_xor(tmax, 32, 64));
      if (!__all(tmax <= mrunA + DEFTH)){
        float mnew = fmaxf(mrunA, tmax);
        float scl = exp2a(mrunA - mnew);
        mrunA = mnew; lrunA *= scl;
        #pragma unroll
        for (int dt = 0; dt < 4; dt++)
          #pragma unroll
          for (int j = 0; j < 4; j++) oaccA[dt][j] *= scl;
      }
      float rs[4];
      #pragma unroll
      for (int mt = 0; mt < 4; mt++){
        float p0 = exp2a(sa[mt][0] - mrunA);
        float p1 = exp2a(sa[mt][1] - mrunA);
        float p2 = exp2a(sa[mt][2] - mrunA);
        float p3 = exp2a(sa[mt][3] - mrunA);
        sa[mt][0] = p0; sa[mt][1] = p1; sa[mt][2] = p2; sa[mt][3] = p3;
        rs[mt] = (p0 + p1) + (p2 + p3);
      }
      float rsum = (rs[0] + rs[1]) + (rs[2] + rs[3]);
      rsum += __shfl_xor(rsum, 16, 64);
      rsum += __shfl_xor(rsum, 32, 64);
      lrunA += rsum;
      u0a.d[0] = cvtpk(sa[0][0], sa[0][1]); u0a.d[1] = cvtpk(sa[0][2], sa[0][3]);
      u0a.d[2] = cvtpk(sa[1][0], sa[1][1]); u0a.d[3] = cvtpk(sa[1][2], sa[1][3]);
      u1a.d[0] = cvtpk(sa[2][0], sa[2][1]); u1a.d[1] = cvtpk(sa[2][2], sa[2][3]);
      u1a.d[2] = cvtpk(sa[3][0], sa[3][1]); u1a.d[3] = cvtpk(sa[3][2], sa[3][3]);
    }
    {
      float tm[4];
      #pragma unroll
      for (int mt = 0; mt < 4; mt++){
        float4 bk = *(const float4*)&mks[buf][mt * 16 + g * 4];
        float s0 = fmaf(sb[mt][0], QKSCL, fminf(bk.x, bnqb));
        float s1 = fmaf(sb[mt][1], QKSCL, fminf(bk.y, bnqb));
        float s2 = fmaf(sb[mt][2], QKSCL, fminf(bk.z, bnqb));
        float s3 = fmaf(sb[mt][3], QKSCL, fminf(bk.w, bnqb));
        sb[mt][0] = s0; sb[mt][1] = s1; sb[mt][2] = s2; sb[mt][3] = s3;
        tm[mt] = fmaxf(fmaxf(s0, s1), fmaxf(s2, s3));
      }
      float tmax = fmaxf(fmaxf(tm[0], tm[1]), fmaxf(tm[2], tm[3]));
      tmax = fmaxf(tmax, __shfl_xor(tmax, 16, 64));
      tmax = fmaxf(tmax, __shfl_xor(tmax, 32, 64));
      if (!__all(tmax <= mrunB + DEFTH)){
        float mnew = fmaxf(mrunB, tmax);
        float scl = exp2a(mrunB - mnew);
        mrunB = mnew; lrunB *= scl;
        #pragma unroll
        for (int dt = 0; dt < 4; dt++)
          #pragma unroll
          for (int j = 0; j < 4; j++) oaccB[dt][j] *= scl;
      }
      float rs[4];
      #pragma unroll
      for (int mt = 0; mt < 4; mt++){
        float p0 = exp2a(sb[mt][0] - mrunB);
        float p1 = exp2a(sb[mt][1] - mrunB);
        float p2 = exp2a(sb[mt][2] - mrunB);
        float p3 = exp2a(sb[mt][3] - mrunB);
        sb[mt][0] = p0; sb[mt][1] = p1; sb[mt][2] = p2; sb[mt][3] = p3;
        rs[mt] = (p0 + p1) + (p2 + p3);
      }
      float rsum = (rs[0] + rs[1]) + (rs[2] + rs[3]);
      rsum += __shfl_xor(rsum, 16, 64);
      rsum += __shfl_xor(rsum, 32, 64);
      lrunB += rsum;
      u0b.d[0] = cvtpk(sb[0][0], sb[0][1]); u0b.d[1] = cvtpk(sb[0][2], sb[0][3]);
      u0b.d[2] = cvtpk(sb[1][0], sb[1][1]); u0b.d[3] = cvtpk(sb[1][2], sb[1][3]);
      u1b.d[0] = cvtpk(sb[2][0], sb[2][1]); u1b.d[1] = cvtpk(sb[2][2], sb[2][3]);
      u1b.d[2] = cvtpk(sb[3][0], sb[3][1]); u1b.d[3] = cvtpk(sb[3][2], sb[3][3]);
    }

    __builtin_amdgcn_s_setprio(1);
    #pragma unroll
    for (int dt = 0; dt < 4; dt++){
      bf16x8 vf0 = *(bf16x8*)&Vts[buf][(dt * 16 + li) * 88 + g * 8];
      bf16x8 vf1 = *(bf16x8*)&Vts[buf][(dt * 16 + li) * 88 + 32 + g * 8];
      oaccA[dt] = __builtin_amdgcn_mfma_f32_16x16x32_bf16(vf0, u0a.v, oaccA[dt], 0, 0, 0);
      oaccA[dt] = __builtin_amdgcn_mfma_f32_16x16x32_bf16(vf1, u1a.v, oaccA[dt], 0, 0, 0);
      oaccB[dt] = __builtin_amdgcn_mfma_f32_16x16x32_bf16(vf0, u0b.v, oaccB[dt], 0, 0, 0);
      oaccB[dt] = __builtin_amdgcn_mfma_f32_16x16x32_bf16(vf1, u1b.v, oaccB[dt], 0, 0, 0);
    }
    __builtin_amdgcn_s_setprio(0);

    if (kt < 15){
      int nb = buf ^ 1;
      *(uint4*)&Ks[nb][sr * 88 + sc]      = kr0;
      *(uint4*)&Ks[nb][sr * 88 + sc + 8]  = kr1;
      *(uint4*)&Vts[nb][sr * 88 + sc]     = vr0;
      *(uint4*)&Vts[nb][sr * 88 + sc + 8] = vr1;
      if (t < 64) mks[nb][t] = mr;
      __syncthreads();
    }
  }

  int b = bh >> 3, h = bh & 7;
  float invA = 1.0f / lrunA, invB = 1.0f / lrunB;
  u16* opA = attnB + (((size_t)(b * 1024 + q0 + w * 32 + li)) << 9) + h * 64 + g * 4;
  u16* opB = opA + (16 << 9);
  #pragma unroll
  for (int dt = 0; dt < 4; dt++){
    union { u32 d[2]; us4 v; } oa, ob;
    oa.d[0] = cvtpk(oaccA[dt][0] * invA, oaccA[dt][1] * invA);
    oa.d[1] = cvtpk(oaccA[dt][2] * invA, oaccA[dt][3] * invA);
    ob.d[0] = cvtpk(oaccB[dt][0] * invB, oaccB[dt][1] * invB);
    ob.d[1] = cvtpk(oaccB[dt][2] * invB, oaccB[dt][3] * invB);
    *(us4*)(opA + dt * 16) = oa.v;
    *(us4*)(opB + dt * 16) = ob.v;
  }
}

// ------------------------------------------------------------------
// 10) LN over C + transpose to (B,C,N). 256 blocks x 32 tokens (was 128x64).
// ------------------------------------------------------------------
__global__ __launch_bounds__(256) void k_ln(const u16* __restrict__ xfB, const u16* __restrict__ attnO,
    const float* __restrict__ gamma, const float* __restrict__ beta, float* __restrict__ out){
  __shared__ float mu_s[32], rs_s[32];
  __shared__ float tile[32][65];
  int b = blockIdx.x >> 5, n0 = (blockIdx.x & 31) << 5;   // grid 256
  int t = threadIdx.x, w = t >> 6, lane = t & 63;

  for (int r = w * 8; r < w * 8 + 8; r++){
    size_t rb = ((size_t)(b * 1024 + n0 + r)) << 9;
    union { uint4 v; u16 u[8]; } av; av.v = *(const uint4*)(attnO + rb + lane * 8);
    union { uint4 v; u16 u[8]; } xv; xv.v = *(const uint4*)(xfB + rb + lane * 8);
    float s = 0.0f, s2 = 0.0f;
    #pragma unroll
    for (int i = 0; i < 8; i++){
      float v = b2f(av.u[i]) + b2f(xv.u[i]);
      s += v; s2 += v * v;
    }
    #pragma unroll
    for (int o = 32; o > 0; o >>= 1){ s += __shfl_xor(s, o, 64); s2 += __shfl_xor(s2, o, 64); }
    if (lane == 0){
      float mu = s * (1.0f / 512.0f);
      float var = s2 * (1.0f / 512.0f) - mu * mu;
      mu_s[r] = mu;
      rs_s[r] = 1.0f / sqrtf(var + 1e-5f);
    }
  }
  __syncthreads();

  for (int ch = 0; ch < 8; ch++){
    int c0 = ch * 64;
    {
      int r = t >> 3, cp = (t & 7) << 3;    // 32 rows x 8 chan-groups
      size_t rb = (((size_t)(b * 1024 + n0 + r)) << 9) + c0 + cp;
      float mu = mu_s[r], rstd = rs_s[r];
      union { uint4 v; u16 u[8]; } av; av.v = *(const uint4*)(attnO + rb);
      union { uint4 v; u16 u[8]; } xv; xv.v = *(const uint4*)(xfB + rb);
      #pragma unroll
      for (int i = 0; i < 8; i++){
        int c = c0 + cp + i;
        float v = b2f(av.u[i]) + b2f(xv.u[i]);
        tile[r][cp + i] = (v - mu) * rstd * gamma[c] + beta[c];
      }
    }
    __syncthreads();
    {
      int cl = t >> 2, np_ = (t & 3) << 3;  // 64 chans x 4 n-groups of 8
      float* op = out + (((size_t)(b * 512 + c0 + cl)) << 10) + n0 + np_;
      float4 v0 = { tile[np_ + 0][cl], tile[np_ + 1][cl], tile[np_ + 2][cl], tile[np_ + 3][cl] };
      float4 v1 = { tile[np_ + 4][cl], tile[np_ + 5][cl], tile[np_ + 6][cl], tile[np_ + 7][cl] };
      *(float4*)op = v0;
      *(float4*)(op + 4) = v1;
    }
    __syncthreads();
  }
}

// ------------------------------------------------------------------
extern "C" void kernel_launch(void* const* d_in, const int* in_sizes, int n_in,
                              void* d_out, int out_size, void* d_ws, size_t ws_size,
                              hipStream_t stream){
  (void)in_sizes; (void)n_in; (void)out_size; (void)ws_size;
  const float* x    = (const float*)d_in[0];
  const float* Wq   = (const float*)d_in[1];
  const float* bq   = (const float*)d_in[2];
  const float* Wk   = (const float*)d_in[3];
  const float* bk   = (const float*)d_in[4];
  const float* Wv   = (const float*)d_in[5];
  const float* bv   = (const float*)d_in[6];
  const float* Wo   = (const float*)d_in[7];
  const float* bo   = (const float*)d_in[8];
  const float* Wsp  = (const float*)d_in[9];
  const float* bsp  = (const float*)d_in[10];
  const float* Wse1 = (const float*)d_in[11];
  const float* bse1 = (const float*)d_in[12];
  const float* Wse2 = (const float*)d_in[13];
  const float* bse2 = (const float*)d_in[14];
  const float* gamma= (const float*)d_in[15];
  const float* beta = (const float*)d_in[16];
  float* out = (float*)d_out;

  char* ws = (char*)d_ws;
  size_t off = 0;
  auto alloc = [&](size_t bytes) -> void* {
    void* p = ws + off;
    off += (bytes + 255) & ~(size_t)255;
    return p;
  };
  u16*   WB     = (u16*)  alloc(1536 * 512 * 2);
  u16*   WoB    = (u16*)  alloc(512 * 512 * 2);
  float* pooled = (float*)alloc(4096 * 4);
  float* cw     = (float*)alloc(4096 * 4);
  float* mbuf   = (float*)alloc(65536 * 4);
  float* bneg   = (float*)alloc(65536 * 4);
  u16*   xfB    = (u16*)  alloc((size_t)8192 * 512 * 2);
  u16*   Qb     = (u16*)  alloc(8388608);
  u16*   Kb     = (u16*)  alloc(8388608);
  u16*   VtG    = (u16*)  alloc(8388608);
  u16*   attnB  = (u16*)  alloc(8388608);
  u16*   attnOb = Qb;   // alias Q (8.4MB) after flash

  k_prep  <<<dim3(2048), dim3(256), 0, stream>>>(Wq, Wk, Wv, Wo, WB, WoB, x, pooled);
  k_se    <<<dim3(8),    dim3(256), 0, stream>>>(pooled, Wse1, bse1, Wse2, bse2, cw);
  k_spxf  <<<dim3(256),  dim3(256), 0, stream>>>(x, Wsp, bsp, cw, mbuf, xfB);
  k_mask  <<<dim3(64),   dim3(64),  0, stream>>>(mbuf, bneg);
  k_gemm_qkv<<<dim3(64, 12), dim3(256), 0, stream>>>(xfB, WB, bq, bk, bv, Qb, Kb, VtG);
  k_flash <<<dim3(512),  dim3(256), 0, stream>>>(Qb, Kb, VtG, bneg, attnB);
  k_gemm_o<<<dim3(64, 4), dim3(256), 0, stream>>>(attnB, WoB, bo, attnOb);
  k_ln    <<<dim3(256),  dim3(256), 0, stream>>>(xfB, attnOb, gamma, beta, out);
}

// Round 13
// 127.836 us; speedup vs baseline: 1.5815x; 1.5815x over previous
//
#include <hip/hip_runtime.h>
#include <hip/hip_bf16.h>
#include <math.h>

typedef unsigned short u16;
typedef unsigned int u32;
typedef __attribute__((ext_vector_type(4))) float f32x4;
typedef __attribute__((ext_vector_type(8))) short bf16x8;
typedef __attribute__((ext_vector_type(4))) unsigned short us4;
typedef __attribute__((ext_vector_type(8))) unsigned short us8;

#define DI __device__ __forceinline__

// natural -1e9 scaled by log2(e): softmax computed in base-2 domain
#define NEGS  (-1.4426950408889634e9f)
#define QKSCL (0.18033688011112042f)     // 0.125 * log2(e)
#define DEFTH (11.541560327111708f)      // 8 * log2(e)

DI u16 f2b(float x){ __hip_bfloat16 h = __float2bfloat16(x); return *reinterpret_cast<u16*>(&h); }
DI float b2f(u16 u){ union { float f; u32 i; } v; v.i = ((u32)u) << 16; return v.f; }

DI u32 cvtpk(float lo, float hi){
  u32 r;
  asm("v_cvt_pk_bf16_f32 %0, %1, %2" : "=v"(r) : "v"(lo), "v"(hi));
  return r;
}
DI float exp2a(float x){
  float r;
  asm("v_exp_f32 %0, %1" : "=v"(r) : "v"(x));
  return r;
}

// direct global->LDS DMA, 16B per lane; LDS dest = wave-uniform base + lane*16
DI void gload16(const void* g, void* l){
  __builtin_amdgcn_global_load_lds((const __attribute__((address_space(1))) void*)g,
                                   (__attribute__((address_space(3))) void*)l, 16, 0, 0);
}

// ------------------------------------------------------------------
// 1+2 merged) k_prep: blocks [0,1024) weights->bf16; [1024,2048) pooled
// ------------------------------------------------------------------
__global__ __launch_bounds__(256) void k_prep(const float* __restrict__ Wq, const float* __restrict__ Wk,
    const float* __restrict__ Wv, const float* __restrict__ Wo,
    u16* __restrict__ WB, u16* __restrict__ WoB,
    const float* __restrict__ x, float* __restrict__ pooled){
  if (blockIdx.x < 1024){
    int i = blockIdx.x * 256 + threadIdx.x;
    WB[i]          = f2b(Wq[i]);
    WB[262144 + i] = f2b(Wk[i]);
    WB[524288 + i] = f2b(Wv[i]);
    WoB[i]         = f2b(Wo[i]);
  } else {
    int row  = (blockIdx.x - 1024) * 4 + (threadIdx.x >> 6);
    int lane = threadIdx.x & 63;
    const float4* p = (const float4*)(x + ((size_t)row << 10));
    float4 v0 = p[lane], v1 = p[lane + 64], v2 = p[lane + 128], v3 = p[lane + 192];
    float s = (v0.x + v0.y + v0.z + v0.w) + (v1.x + v1.y + v1.z + v1.w)
            + (v2.x + v2.y + v2.z + v2.w) + (v3.x + v3.y + v3.z + v3.w);
    #pragma unroll
    for (int o = 32; o > 0; o >>= 1) s += __shfl_down(s, o, 64);
    if (lane == 0) pooled[row] = s * (1.0f / 1024.0f);
  }
}

// ------------------------------------------------------------------
// 3) SE
// ------------------------------------------------------------------
__global__ __launch_bounds__(256) void k_se(const float* __restrict__ pooled,
    const float* __restrict__ Wse1, const float* __restrict__ bse1,
    const float* __restrict__ Wse2, const float* __restrict__ bse2,
    float* __restrict__ cw){
  __shared__ float pl[512];
  __shared__ float h1[32];
  int b = blockIdx.x, t = threadIdx.x;
  pl[t] = pooled[b * 512 + t];
  pl[t + 256] = pooled[b * 512 + t + 256];
  __syncthreads();
  if (t < 32){
    float acc = bse1[t];
    const float* w = Wse1 + t * 512;
    for (int c = 0; c < 512; c++) acc = fmaf(pl[c], w[c], acc);
    h1[t] = fmaxf(acc, 0.0f);
  }
  __syncthreads();
  for (int c = t; c < 512; c += 256){
    float acc = bse2[c];
    const float* w = Wse2 + c * 32;
    #pragma unroll
    for (int j = 0; j < 32; j++) acc = fmaf(h1[j], w[j], acc);
    cw[b * 512 + c] = 1.0f / (1.0f + expf(-acc));
  }
}

// ------------------------------------------------------------------
// 4+6 fused) k_spxf: one pass over x producing mbuf (f32) + xfB (bf16^T)
// ------------------------------------------------------------------
__global__ __launch_bounds__(256) void k_spxf(const float* __restrict__ x,
    const float* __restrict__ Wsp, const float* __restrict__ bsp,
    const float* __restrict__ cw, float* __restrict__ mbuf, u16* __restrict__ xfB){
  __shared__ float wsh[4096];
  __shared__ float cwl[512];
  __shared__ float tile[64][36];
  __shared__ float part[8][256];
  int t = threadIdx.x;
  int b = blockIdx.x >> 5, n0 = (blockIdx.x & 31) << 5;
  for (int i = t; i < 4096; i += 256) wsh[i] = Wsp[i];
  cwl[t] = cw[b * 512 + t];
  cwl[t + 256] = cw[b * 512 + t + 256];

  int nl = t & 31, cg = t >> 5;
  int lr = t >> 2, lc = (t & 3) << 3;
  float acc[8] = {0,0,0,0,0,0,0,0};

  for (int cb = 0; cb < 8; cb++){
    __syncthreads();
    const float* xp = x + ((size_t)(b * 512 + cb * 64 + lr) << 10) + n0 + lc;
    float4 v0 = *(const float4*)xp;
    float4 v1 = *(const float4*)(xp + 4);
    *(float4*)&tile[lr][lc]     = v0;
    *(float4*)&tile[lr][lc + 4] = v1;
    __syncthreads();
    float sc[8];
    #pragma unroll
    for (int i = 0; i < 8; i++){
      int c = cb * 64 + cg * 8 + i;
      float v = tile[cg * 8 + i][nl];
      sc[i] = v * cwl[c];
      #pragma unroll
      for (int h = 0; h < 8; h++) acc[h] = fmaf(v, wsh[(h << 9) + c], acc[h]);
    }
    union { u32 d[4]; us8 v; } xu;
    #pragma unroll
    for (int i = 0; i < 4; i++) xu.d[i] = cvtpk(sc[2*i], sc[2*i+1]);
    *(us8*)&xfB[(((size_t)(b * 1024 + n0 + nl)) << 9) + cb * 64 + cg * 8] = xu.v;
  }
  #pragma unroll
  for (int h = 0; h < 8; h++) part[cg][h * 32 + nl] = acc[h];
  __syncthreads();
  {
    int h = t >> 5, px = t & 31;
    float s = bsp[h];
    #pragma unroll
    for (int g2 = 0; g2 < 8; g2++) s += part[g2][h * 32 + px];
    mbuf[(((size_t)(b * 8 + h)) << 10) + n0 + px] = 1.0f / (1.0f + expf(-s));
  }
}

// ------------------------------------------------------------------
// 5) adaptive pool 7x7, threshold, upsample -> bneg (B,8,N) in {0, NEGS}
// ------------------------------------------------------------------
__global__ void k_mask(const float* __restrict__ mbuf, float* __restrict__ bneg){
  __shared__ float sm[1024];
  __shared__ float mg[49];
  int bh = blockIdx.x, t = threadIdx.x;
  const float* mp = mbuf + ((size_t)bh << 10);
  for (int i = t; i < 1024; i += 64) sm[i] = mp[i];
  __syncthreads();
  if (t < 49){
    int ci = t / 7, cj = t % 7;
    int r0 = (ci * 32) / 7, r1 = ((ci + 1) * 32 + 6) / 7;
    int c0 = (cj * 32) / 7, c1 = ((cj + 1) * 32 + 6) / 7;
    float acc = 0.0f;
    for (int cc = c0; cc < c1; cc++){
      float rs = 0.0f;
      for (int rr = r0; rr < r1; rr++) rs += sm[rr * 32 + cc];
      acc += rs / (float)(r1 - r0);
    }
    float v = acc / (float)(c1 - c0);
    mg[t] = (v > 0.5f) ? 1.0f : 0.0f;
  }
  __syncthreads();
  for (int i = t; i < 1024; i += 64){
    int r = i >> 5, c = i & 31;
    float m = mg[((r * 7) >> 5) * 7 + ((c * 7) >> 5)];
    bneg[((size_t)bh << 10) + i] = (m > 0.5f) ? 0.0f : NEGS;
  }
}

// ------------------------------------------------------------------
// 7/9) bf16 MFMA GEMM — dbuf global_load_lds(16B), BK=32, one barrier/step.
//   Plain __launch_bounds__(256): (256,4) forced VGPR 132->64 and spilled
//   (r12: WRITE_SIZE 299MB scratch, 103us). Let allocator use ~132.
// ------------------------------------------------------------------
template<int MODE>
DI void gemm_body(const u16* __restrict__ A, const u16* __restrict__ Bw,
    const float* __restrict__ b0, const float* __restrict__ b1, const float* __restrict__ b2,
    u16* __restrict__ outQ, u16* __restrict__ outK, u16* __restrict__ outV, u16* __restrict__ outO){
  __shared__ __align__(16) u16 smem[16384];
  int m0 = blockIdx.x * 128, n0 = blockIdx.y * 128;
  bool vblk = (MODE == 0) && (n0 >= 1024);
  int t = threadIdx.x, lane = t & 63, w = t >> 6;
  int wr = w >> 1, wc = w & 1;
  int g = lane >> 4, li = lane & 15;
  f32x4 acc[4][4];
  #pragma unroll
  for (int mt = 0; mt < 4; mt++)
    #pragma unroll
    for (int nt = 0; nt < 4; nt++) acc[mt][nt] = (f32x4){0.f, 0.f, 0.f, 0.f};

  int cof = (((lane & 3) ^ ((lane >> 3) & 3)) << 3);
  int rl = lane >> 2;
  const u16* gA = A  + (size_t)(m0 + w * 32 + rl) * 512 + cof;
  const u16* gB = Bw + (size_t)(n0 + w * 32 + rl) * 512 + cof;
  u16* lA = smem + (w * 32) * 32;
  u16* lB = smem + 4096 + (w * 32) * 32;

  #define STAGE(buf, k0)                                              \
    gload16(gA + (k0),            lA + (buf) * 8192);                 \
    gload16(gA + (k0) + 16 * 512, lA + (buf) * 8192 + 512);           \
    gload16(gB + (k0),            lB + (buf) * 8192);                 \
    gload16(gB + (k0) + 16 * 512, lB + (buf) * 8192 + 512);

  STAGE(0, 0);
  __syncthreads();

  int rsw = ((li >> 1) & 3);
  int cA = (g ^ rsw) << 3;
  int cur = 0;
  for (int ks = 0; ks < 16; ks++){
    if (ks < 15){ STAGE(cur ^ 1, (ks + 1) * 32); }
    const u16* Ac = smem + cur * 8192;
    const u16* Bc = smem + cur * 8192 + 4096;
    bf16x8 afr[4], bfr[4];
    #pragma unroll
    for (int mt = 0; mt < 4; mt++)
      afr[mt] = *(const bf16x8*)&Ac[(wr * 64 + mt * 16 + li) * 32 + cA];
    #pragma unroll
    for (int nt = 0; nt < 4; nt++)
      bfr[nt] = *(const bf16x8*)&Bc[(wc * 64 + nt * 16 + li) * 32 + cA];
    if (vblk){
      #pragma unroll
      for (int mt = 0; mt < 4; mt++)
        #pragma unroll
        for (int nt = 0; nt < 4; nt++)
          acc[mt][nt] = __builtin_amdgcn_mfma_f32_16x16x32_bf16(afr[mt], bfr[nt], acc[mt][nt], 0, 0, 0);
    } else {
      #pragma unroll
      for (int mt = 0; mt < 4; mt++)
        #pragma unroll
        for (int nt = 0; nt < 4; nt++)
          acc[mt][nt] = __builtin_amdgcn_mfma_f32_16x16x32_bf16(bfr[nt], afr[mt], acc[mt][nt], 0, 0, 0);
    }
    __syncthreads();
    cur ^= 1;
  }
  #undef STAGE

  // ---- two-pass LDS-staged coalesced epilogue
  u16* Cl = smem;   // 64 x 136
  const float* bb = vblk ? b2 : ((MODE == 0 && (n0 >> 9)) ? b1 : b0);
  #pragma unroll
  for (int p = 0; p < 2; p++){
    __syncthreads();
    if (vblk){
      if (wc == p){
        #pragma unroll
        for (int mt = 0; mt < 4; mt++){
          #pragma unroll
          for (int nt = 0; nt < 4; nt++){
            int row = nt * 16 + li;
            float bias = bb[(n0 & 511) + p * 64 + row];
            int col = wr * 64 + ((mt >> 1) << 5) + (g << 3) + ((mt & 1) << 2);
            union { u32 d[2]; us4 v; } pu;
            pu.d[0] = cvtpk(acc[mt][nt][0] + bias, acc[mt][nt][1] + bias);
            pu.d[1] = cvtpk(acc[mt][nt][2] + bias, acc[mt][nt][3] + bias);
            *(us4*)&Cl[row * 136 + col] = pu.v;
          }
        }
      }
    } else {
      if (wr == p){
        #pragma unroll
        for (int mt = 0; mt < 4; mt++){
          #pragma unroll
          for (int nt = 0; nt < 4; nt++){
            int row = mt * 16 + li;
            int ob = wc * 64 + nt * 16 + (g << 2);
            float4 bias4 = *(const float4*)&bb[(n0 & 511) + ob];
            union { u32 d[2]; us4 v; } pu;
            pu.d[0] = cvtpk(acc[mt][nt][0] + bias4.x, acc[mt][nt][1] + bias4.y);
            pu.d[1] = cvtpk(acc[mt][nt][2] + bias4.z, acc[mt][nt][3] + bias4.w);
            *(us4*)&Cl[row * 136 + ob] = pu.v;
          }
        }
      }
    }
    __syncthreads();
    int r = t >> 4, ol = (t & 15) << 3;
    if (vblk){
      int b = m0 >> 10, nt0 = m0 & 1023;
      #pragma unroll
      for (int pp = 0; pp < 4; pp++){
        int rr = pp * 16 + r;
        int c = (n0 & 511) + p * 64 + rr, h = c >> 6, dv = c & 63;
        us8 v = *(us8*)&Cl[rr * 136 + ol];
        *(us8*)&outV[(((size_t)(b * 8 + h)) << 16) + ((size_t)dv << 10) + nt0 + ol] = v;
      }
    } else if (MODE == 0){
      u16* base = (n0 >> 9) ? outK : outQ;
      #pragma unroll
      for (int pp = 0; pp < 4; pp++){
        int rr = pp * 16 + r;
        int m = m0 + p * 64 + rr, b = m >> 10, n = m & 1023;
        int c = (n0 & 511) + ol, h = c >> 6, dv = c & 63;
        us8 v = *(us8*)&Cl[rr * 136 + ol];
        *(us8*)&base[(((size_t)(b * 8 + h)) << 16) + ((size_t)n << 6) + dv] = v;
      }
    } else {
      #pragma unroll
      for (int pp = 0; pp < 4; pp++){
        int rr = pp * 16 + r;
        int m = m0 + p * 64 + rr;
        us8 v = *(us8*)&Cl[rr * 136 + ol];
        *(us8*)&outO[((size_t)m << 9) + n0 + ol] = v;
      }
    }
  }
}

__global__ __launch_bounds__(256) void k_gemm_qkv(const u16* __restrict__ A, const u16* __restrict__ Bw,
    const float* __restrict__ b0, const float* __restrict__ b1, const float* __restrict__ b2,
    u16* __restrict__ outQ, u16* __restrict__ outK, u16* __restrict__ outV){
  gemm_body<0>(A, Bw, b0, b1, b2, outQ, outK, outV, nullptr);
}

__global__ __launch_bounds__(256) void k_gemm_o(const u16* __restrict__ A, const u16* __restrict__ Bw,
    const float* __restrict__ b0, u16* __restrict__ outO){
  gemm_body<1>(A, Bw, b0, nullptr, nullptr, nullptr, nullptr, nullptr, outO);
}

// ------------------------------------------------------------------
// 8) flash attention: 32 q-rows/wave, pitch-88 LDS, dbuf, base-2 softmax,
//    cvt_pk, defer-max, XCD swizzle, setprio. (proven r11 structure)
// ------------------------------------------------------------------
__global__ __launch_bounds__(256) void k_flash(const u16* __restrict__ Q, const u16* __restrict__ K,
    const u16* __restrict__ Vt, const float* __restrict__ bneg, u16* __restrict__ attnB){
  __shared__ __align__(16) u16 Ks[2][64 * 88];
  __shared__ __align__(16) u16 Vts[2][64 * 88];
  __shared__ float mks[2][64];
  int hw = blockIdx.x;
  int bid = ((hw & 7) << 6) + (hw >> 3);
  int bh = bid >> 3, q0 = (bid & 7) << 7;
  int t = threadIdx.x, lane = t & 63, w = t >> 6;
  int g = lane >> 4, li = lane & 15;

  const u16* Kp = K  + ((size_t)bh << 16);
  const u16* Vp = Vt + ((size_t)bh << 16);
  const float* bp = bneg + ((size_t)bh << 10);

  bf16x8 qf0a, qf1a, qf0b, qf1b;
  {
    const u16* qra = Q + ((size_t)bh << 16) + ((size_t)(q0 + w * 32 + li) << 6);
    qf0a = *(const bf16x8*)(qra + g * 8);
    qf1a = *(const bf16x8*)(qra + 32 + g * 8);
    const u16* qrb = qra + (16 << 6);
    qf0b = *(const bf16x8*)(qrb + g * 8);
    qf1b = *(const bf16x8*)(qrb + 32 + g * 8);
  }
  float bnqa = bp[q0 + w * 32 + li];
  float bnqb = bp[q0 + w * 32 + 16 + li];

  f32x4 oaccA[4], oaccB[4];
  #pragma unroll
  for (int dt = 0; dt < 4; dt++){
    oaccA[dt] = (f32x4){0.f, 0.f, 0.f, 0.f};
    oaccB[dt] = (f32x4){0.f, 0.f, 0.f, 0.f};
  }
  float mrunA = -INFINITY, lrunA = 0.0f, mrunB = -INFINITY, lrunB = 0.0f;

  int sr = t >> 2, sc = (t & 3) << 4;
  const u16* kg = Kp + ((size_t)sr << 6) + sc;
  const u16* vg = Vp + ((size_t)sr << 10) + sc;
  uint4 kr0 = *(const uint4*)(kg), kr1 = *(const uint4*)(kg + 8);
  uint4 vr0 = *(const uint4*)(vg), vr1 = *(const uint4*)(vg + 8);
  float mr = (t < 64) ? bp[t] : 0.0f;

  *(uint4*)&Ks[0][sr * 88 + sc]      = kr0;
  *(uint4*)&Ks[0][sr * 88 + sc + 8]  = kr1;
  *(uint4*)&Vts[0][sr * 88 + sc]     = vr0;
  *(uint4*)&Vts[0][sr * 88 + sc + 8] = vr1;
  if (t < 64) mks[0][t] = mr;
  __syncthreads();

  for (int kt = 0; kt < 16; kt++){
    int buf = kt & 1;
    if (kt < 15){
      kr0 = *(const uint4*)(kg + (kt + 1) * 4096);
      kr1 = *(const uint4*)(kg + (kt + 1) * 4096 + 8);
      vr0 = *(const uint4*)(vg + (kt + 1) * 64);
      vr1 = *(const uint4*)(vg + (kt + 1) * 64 + 8);
      if (t < 64) mr = bp[(kt + 1) * 64 + t];
    }

    f32x4 sa[4], sb[4];
    #pragma unroll
    for (int mt = 0; mt < 4; mt++){ sa[mt] = (f32x4){0.f,0.f,0.f,0.f}; sb[mt] = (f32x4){0.f,0.f,0.f,0.f}; }
    __builtin_amdgcn_s_setprio(1);
    #pragma unroll
    for (int mt = 0; mt < 4; mt++){
      bf16x8 kf0 = *(bf16x8*)&Ks[buf][(mt * 16 + li) * 88 + g * 8];
      bf16x8 kf1 = *(bf16x8*)&Ks[buf][(mt * 16 + li) * 88 + 32 + g * 8];
      sa[mt] = __builtin_amdgcn_mfma_f32_16x16x32_bf16(kf0, qf0a, sa[mt], 0, 0, 0);
      sa[mt] = __builtin_amdgcn_mfma_f32_16x16x32_bf16(kf1, qf1a, sa[mt], 0, 0, 0);
      sb[mt] = __builtin_amdgcn_mfma_f32_16x16x32_bf16(kf0, qf0b, sb[mt], 0, 0, 0);
      sb[mt] = __builtin_amdgcn_mfma_f32_16x16x32_bf16(kf1, qf1b, sb[mt], 0, 0, 0);
    }
    __builtin_amdgcn_s_setprio(0);

    union { u32 d[4]; bf16x8 v; } u0a, u1a, u0b, u1b;
    {
      float tm[4];
      #pragma unroll
      for (int mt = 0; mt < 4; mt++){
        float4 bk = *(const float4*)&mks[buf][mt * 16 + g * 4];
        float s0 = fmaf(sa[mt][0], QKSCL, fminf(bk.x, bnqa));
        float s1 = fmaf(sa[mt][1], QKSCL, fminf(bk.y, bnqa));
        float s2 = fmaf(sa[mt][2], QKSCL, fminf(bk.z, bnqa));
        float s3 = fmaf(sa[mt][3], QKSCL, fminf(bk.w, bnqa));
        sa[mt][0] = s0; sa[mt][1] = s1; sa[mt][2] = s2; sa[mt][3] = s3;
        tm[mt] = fmaxf(fmaxf(s0, s1), fmaxf(s2, s3));
      }
      float tmax = fmaxf(fmaxf(tm[0], tm[1]), fmaxf(tm[2], tm[3]));
      tmax = fmaxf(tmax, __shfl_xor(tmax, 16, 64));
      tmax = fmaxf(tmax, __shfl_xor(tmax, 32, 64));
      if (!__all(tmax <= mrunA + DEFTH)){
        float mnew = fmaxf(mrunA, tmax);
        float scl = exp2a(mrunA - mnew);
        mrunA = mnew; lrunA *= scl;
        #pragma unroll
        for (int dt = 0; dt < 4; dt++)
          #pragma unroll
          for (int j = 0; j < 4; j++) oaccA[dt][j] *= scl;
      }
      float rs[4];
      #pragma unroll
      for (int mt = 0; mt < 4; mt++){
        float p0 = exp2a(sa[mt][0] - mrunA);
        float p1 = exp2a(sa[mt][1] - mrunA);
        float p2 = exp2a(sa[mt][2] - mrunA);
        float p3 = exp2a(sa[mt][3] - mrunA);
        sa[mt][0] = p0; sa[mt][1] = p1; sa[mt][2] = p2; sa[mt][3] = p3;
        rs[mt] = (p0 + p1) + (p2 + p3);
      }
      float rsum = (rs[0] + rs[1]) + (rs[2] + rs[3]);
      rsum += __shfl_xor(rsum, 16, 64);
      rsum += __shfl_xor(rsum, 32, 64);
      lrunA += rsum;
      u0a.d[0] = cvtpk(sa[0][0], sa[0][1]); u0a.d[1] = cvtpk(sa[0][2], sa[0][3]);
      u0a.d[2] = cvtpk(sa[1][0], sa[1][1]); u0a.d[3] = cvtpk(sa[1][2], sa[1][3]);
      u1a.d[0] = cvtpk(sa[2][0], sa[2][1]); u1a.d[1] = cvtpk(sa[2][2], sa[2][3]);
      u1a.d[2] = cvtpk(sa[3][0], sa[3][1]); u1a.d[3] = cvtpk(sa[3][2], sa[3][3]);
    }
    {
      float tm[4];
      #pragma unroll
      for (int mt = 0; mt < 4; mt++){
        float4 bk = *(const float4*)&mks[buf][mt * 16 + g * 4];
        float s0 = fmaf(sb[mt][0], QKSCL, fminf(bk.x, bnqb));
        float s1 = fmaf(sb[mt][1], QKSCL, fminf(bk.y, bnqb));
        float s2 = fmaf(sb[mt][2], QKSCL, fminf(bk.z, bnqb));
        float s3 = fmaf(sb[mt][3], QKSCL, fminf(bk.w, bnqb));
        sb[mt][0] = s0; sb[mt][1] = s1; sb[mt][2] = s2; sb[mt][3] = s3;
        tm[mt] = fmaxf(fmaxf(s0, s1), fmaxf(s2, s3));
      }
      float tmax = fmaxf(fmaxf(tm[0], tm[1]), fmaxf(tm[2], tm[3]));
      tmax = fmaxf(tmax, __shfl_xor(tmax, 16, 64));
      tmax = fmaxf(tmax, __shfl_xor(tmax, 32, 64));
      if (!__all(tmax <= mrunB + DEFTH)){
        float mnew = fmaxf(mrunB, tmax);
        float scl = exp2a(mrunB - mnew);
        mrunB = mnew; lrunB *= scl;
        #pragma unroll
        for (int dt = 0; dt < 4; dt++)
          #pragma unroll
          for (int j = 0; j < 4; j++) oaccB[dt][j] *= scl;
      }
      float rs[4];
      #pragma unroll
      for (int mt = 0; mt < 4; mt++){
        float p0 = exp2a(sb[mt][0] - mrunB);
        float p1 = exp2a(sb[mt][1] - mrunB);
        float p2 = exp2a(sb[mt][2] - mrunB);
        float p3 = exp2a(sb[mt][3] - mrunB);
        sb[mt][0] = p0; sb[mt][1] = p1; sb[mt][2] = p2; sb[mt][3] = p3;
        rs[mt] = (p0 + p1) + (p2 + p3);
      }
      float rsum = (rs[0] + rs[1]) + (rs[2] + rs[3]);
      rsum += __shfl_xor(rsum, 16, 64);
      rsum += __shfl_xor(rsum, 32, 64);
      lrunB += rsum;
      u0b.d[0] = cvtpk(sb[0][0], sb[0][1]); u0b.d[1] = cvtpk(sb[0][2], sb[0][3]);
      u0b.d[2] = cvtpk(sb[1][0], sb[1][1]); u0b.d[3] = cvtpk(sb[1][2], sb[1][3]);
      u1b.d[0] = cvtpk(sb[2][0], sb[2][1]); u1b.d[1] = cvtpk(sb[2][2], sb[2][3]);
      u1b.d[2] = cvtpk(sb[3][0], sb[3][1]); u1b.d[3] = cvtpk(sb[3][2], sb[3][3]);
    }

    __builtin_amdgcn_s_setprio(1);
    #pragma unroll
    for (int dt = 0; dt < 4; dt++){
      bf16x8 vf0 = *(bf16x8*)&Vts[buf][(dt * 16 + li) * 88 + g * 8];
      bf16x8 vf1 = *(bf16x8*)&Vts[buf][(dt * 16 + li) * 88 + 32 + g * 8];
      oaccA[dt] = __builtin_amdgcn_mfma_f32_16x16x32_bf16(vf0, u0a.v, oaccA[dt], 0, 0, 0);
      oaccA[dt] = __builtin_amdgcn_mfma_f32_16x16x32_bf16(vf1, u1a.v, oaccA[dt], 0, 0, 0);
      oaccB[dt] = __builtin_amdgcn_mfma_f32_16x16x32_bf16(vf0, u0b.v, oaccB[dt], 0, 0, 0);
      oaccB[dt] = __builtin_amdgcn_mfma_f32_16x16x32_bf16(vf1, u1b.v, oaccB[dt], 0, 0, 0);
    }
    __builtin_amdgcn_s_setprio(0);

    if (kt < 15){
      int nb = buf ^ 1;
      *(uint4*)&Ks[nb][sr * 88 + sc]      = kr0;
      *(uint4*)&Ks[nb][sr * 88 + sc + 8]  = kr1;
      *(uint4*)&Vts[nb][sr * 88 + sc]     = vr0;
      *(uint4*)&Vts[nb][sr * 88 + sc + 8] = vr1;
      if (t < 64) mks[nb][t] = mr;
      __syncthreads();
    }
  }

  int b = bh >> 3, h = bh & 7;
  float invA = 1.0f / lrunA, invB = 1.0f / lrunB;
  u16* opA = attnB + (((size_t)(b * 1024 + q0 + w * 32 + li)) << 9) + h * 64 + g * 4;
  u16* opB = opA + (16 << 9);
  #pragma unroll
  for (int dt = 0; dt < 4; dt++){
    union { u32 d[2]; us4 v; } oa, ob;
    oa.d[0] = cvtpk(oaccA[dt][0] * invA, oaccA[dt][1] * invA);
    oa.d[1] = cvtpk(oaccA[dt][2] * invA, oaccA[dt][3] * invA);
    ob.d[0] = cvtpk(oaccB[dt][0] * invB, oaccB[dt][1] * invB);
    ob.d[1] = cvtpk(oaccB[dt][2] * invB, oaccB[dt][3] * invB);
    *(us4*)(opA + dt * 16) = oa.v;
    *(us4*)(opB + dt * 16) = ob.v;
  }
}

// ------------------------------------------------------------------
// 10) LN over C + transpose to (B,C,N). 256 blocks x 32 tokens.
// ------------------------------------------------------------------
__global__ __launch_bounds__(256) void k_ln(const u16* __restrict__ xfB, const u16* __restrict__ attnO,
    const float* __restrict__ gamma, const float* __restrict__ beta, float* __restrict__ out){
  __shared__ float mu_s[32], rs_s[32];
  __shared__ float tile[32][65];
  int b = blockIdx.x >> 5, n0 = (blockIdx.x & 31) << 5;   // grid 256
  int t = threadIdx.x, w = t >> 6, lane = t & 63;

  for (int r = w * 8; r < w * 8 + 8; r++){
    size_t rb = ((size_t)(b * 1024 + n0 + r)) << 9;
    union { uint4 v; u16 u[8]; } av; av.v = *(const uint4*)(attnO + rb + lane * 8);
    union { uint4 v; u16 u[8]; } xv; xv.v = *(const uint4*)(xfB + rb + lane * 8);
    float s = 0.0f, s2 = 0.0f;
    #pragma unroll
    for (int i = 0; i < 8; i++){
      float v = b2f(av.u[i]) + b2f(xv.u[i]);
      s += v; s2 += v * v;
    }
    #pragma unroll
    for (int o = 32; o > 0; o >>= 1){ s += __shfl_xor(s, o, 64); s2 += __shfl_xor(s2, o, 64); }
    if (lane == 0){
      float mu = s * (1.0f / 512.0f);
      float var = s2 * (1.0f / 512.0f) - mu * mu;
      mu_s[r] = mu;
      rs_s[r] = 1.0f / sqrtf(var + 1e-5f);
    }
  }
  __syncthreads();

  for (int ch = 0; ch < 8; ch++){
    int c0 = ch * 64;
    {
      int r = t >> 3, cp = (t & 7) << 3;    // 32 rows x 8 chan-groups
      size_t rb = (((size_t)(b * 1024 + n0 + r)) << 9) + c0 + cp;
      float mu = mu_s[r], rstd = rs_s[r];
      union { uint4 v; u16 u[8]; } av; av.v = *(const uint4*)(attnO + rb);
      union { uint4 v; u16 u[8]; } xv; xv.v = *(const uint4*)(xfB + rb);
      #pragma unroll
      for (int i = 0; i < 8; i++){
        int c = c0 + cp + i;
        float v = b2f(av.u[i]) + b2f(xv.u[i]);
        tile[r][cp + i] = (v - mu) * rstd * gamma[c] + beta[c];
      }
    }
    __syncthreads();
    {
      int cl = t >> 2, np_ = (t & 3) << 3;  // 64 chans x 4 n-groups of 8
      float* op = out + (((size_t)(b * 512 + c0 + cl)) << 10) + n0 + np_;
      float4 v0 = { tile[np_ + 0][cl], tile[np_ + 1][cl], tile[np_ + 2][cl], tile[np_ + 3][cl] };
      float4 v1 = { tile[np_ + 4][cl], tile[np_ + 5][cl], tile[np_ + 6][cl], tile[np_ + 7][cl] };
      *(float4*)op = v0;
      *(float4*)(op + 4) = v1;
    }
    __syncthreads();
  }
}

// ------------------------------------------------------------------
extern "C" void kernel_launch(void* const* d_in, const int* in_sizes, int n_in,
                              void* d_out, int out_size, void* d_ws, size_t ws_size,
                              hipStream_t stream){
  (void)in_sizes; (void)n_in; (void)out_size; (void)ws_size;
  const float* x    = (const float*)d_in[0];
  const float* Wq   = (const float*)d_in[1];
  const float* bq   = (const float*)d_in[2];
  const float* Wk   = (const float*)d_in[3];
  const float* bk   = (const float*)d_in[4];
  const float* Wv   = (const float*)d_in[5];
  const float* bv   = (const float*)d_in[6];
  const float* Wo   = (const float*)d_in[7];
  const float* bo   = (const float*)d_in[8];
  const float* Wsp  = (const float*)d_in[9];
  const float* bsp  = (const float*)d_in[10];
  const float* Wse1 = (const float*)d_in[11];
  const float* bse1 = (const float*)d_in[12];
  const float* Wse2 = (const float*)d_in[13];
  const float* bse2 = (const float*)d_in[14];
  const float* gamma= (const float*)d_in[15];
  const float* beta = (const float*)d_in[16];
  float* out = (float*)d_out;

  char* ws = (char*)d_ws;
  size_t off = 0;
  auto alloc = [&](size_t bytes) -> void* {
    void* p = ws + off;
    off += (bytes + 255) & ~(size_t)255;
    return p;
  };
  u16*   WB     = (u16*)  alloc(1536 * 512 * 2);
  u16*   WoB    = (u16*)  alloc(512 * 512 * 2);
  float* pooled = (float*)alloc(4096 * 4);
  float* cw     = (float*)alloc(4096 * 4);
  float* mbuf   = (float*)alloc(65536 * 4);
  float* bneg   = (float*)alloc(65536 * 4);
  u16*   xfB    = (u16*)  alloc((size_t)8192 * 512 * 2);
  u16*   Qb     = (u16*)  alloc(8388608);
  u16*   Kb     = (u16*)  alloc(8388608);
  u16*   VtG    = (u16*)  alloc(8388608);
  u16*   attnB  = (u16*)  alloc(8388608);
  u16*   attnOb = Qb;   // alias Q (8.4MB) after flash

  k_prep  <<<dim3(2048), dim3(256), 0, stream>>>(Wq, Wk, Wv, Wo, WB, WoB, x, pooled);
  k_se    <<<dim3(8),    dim3(256), 0, stream>>>(pooled, Wse1, bse1, Wse2, bse2, cw);
  k_spxf  <<<dim3(256),  dim3(256), 0, stream>>>(x, Wsp, bsp, cw, mbuf, xfB);
  k_mask  <<<dim3(64),   dim3(64),  0, stream>>>(mbuf, bneg);
  k_gemm_qkv<<<dim3(64, 12), dim3(256), 0, stream>>>(xfB, WB, bq, bk, bv, Qb, Kb, VtG);
  k_flash <<<dim3(512),  dim3(256), 0, stream>>>(Qb, Kb, VtG, bneg, attnB);
  k_gemm_o<<<dim3(64, 4), dim3(256), 0, stream>>>(attnB, WoB, bo, attnOb);
  k_ln    <<<dim3(256),  dim3(256), 0, stream>>>(xfB, attnOb, gamma, beta, out);
}

// Round 14
// 125.284 us; speedup vs baseline: 1.6137x; 1.0204x over previous
//
#include <hip/hip_runtime.h>
#include <hip/hip_bf16.h>
#include <math.h>

typedef unsigned short u16;
typedef unsigned int u32;
typedef __attribute__((ext_vector_type(4))) float f32x4;
typedef __attribute__((ext_vector_type(8))) short bf16x8;
typedef __attribute__((ext_vector_type(4))) unsigned short us4;
typedef __attribute__((ext_vector_type(8))) unsigned short us8;

#define DI __device__ __forceinline__

// natural -1e9 scaled by log2(e): softmax computed in base-2 domain
#define NEGS  (-1.4426950408889634e9f)
#define QKSCL (0.18033688011112042f)     // 0.125 * log2(e)
#define DEFTH (11.541560327111708f)      // 8 * log2(e)

DI u16 f2b(float x){ __hip_bfloat16 h = __float2bfloat16(x); return *reinterpret_cast<u16*>(&h); }
DI float b2f(u16 u){ union { float f; u32 i; } v; v.i = ((u32)u) << 16; return v.f; }

DI u32 cvtpk(float lo, float hi){
  u32 r;
  asm("v_cvt_pk_bf16_f32 %0, %1, %2" : "=v"(r) : "v"(lo), "v"(hi));
  return r;
}
DI float exp2a(float x){
  float r;
  asm("v_exp_f32 %0, %1" : "=v"(r) : "v"(x));
  return r;
}

// direct global->LDS DMA, 16B per lane; LDS dest = wave-uniform base + lane*16
DI void gload16(const void* g, void* l){
  __builtin_amdgcn_global_load_lds((const __attribute__((address_space(1))) void*)g,
                                   (__attribute__((address_space(3))) void*)l, 16, 0, 0);
}

// ------------------------------------------------------------------
// 1+2 merged) k_prep: blocks [0,1024) weights->bf16; [1024,2048) pooled
// ------------------------------------------------------------------
__global__ __launch_bounds__(256) void k_prep(const float* __restrict__ Wq, const float* __restrict__ Wk,
    const float* __restrict__ Wv, const float* __restrict__ Wo,
    u16* __restrict__ WB, u16* __restrict__ WoB,
    const float* __restrict__ x, float* __restrict__ pooled){
  if (blockIdx.x < 1024){
    int i = blockIdx.x * 256 + threadIdx.x;
    WB[i]          = f2b(Wq[i]);
    WB[262144 + i] = f2b(Wk[i]);
    WB[524288 + i] = f2b(Wv[i]);
    WoB[i]         = f2b(Wo[i]);
  } else {
    int row  = (blockIdx.x - 1024) * 4 + (threadIdx.x >> 6);
    int lane = threadIdx.x & 63;
    const float4* p = (const float4*)(x + ((size_t)row << 10));
    float4 v0 = p[lane], v1 = p[lane + 64], v2 = p[lane + 128], v3 = p[lane + 192];
    float s = (v0.x + v0.y + v0.z + v0.w) + (v1.x + v1.y + v1.z + v1.w)
            + (v2.x + v2.y + v2.z + v2.w) + (v3.x + v3.y + v3.z + v3.w);
    #pragma unroll
    for (int o = 32; o > 0; o >>= 1) s += __shfl_down(s, o, 64);
    if (lane == 0) pooled[row] = s * (1.0f / 1024.0f);
  }
}

// ------------------------------------------------------------------
// 3) SE
// ------------------------------------------------------------------
__global__ __launch_bounds__(256) void k_se(const float* __restrict__ pooled,
    const float* __restrict__ Wse1, const float* __restrict__ bse1,
    const float* __restrict__ Wse2, const float* __restrict__ bse2,
    float* __restrict__ cw){
  __shared__ float pl[512];
  __shared__ float h1[32];
  int b = blockIdx.x, t = threadIdx.x;
  pl[t] = pooled[b * 512 + t];
  pl[t + 256] = pooled[b * 512 + t + 256];
  __syncthreads();
  if (t < 32){
    float acc = bse1[t];
    const float* w = Wse1 + t * 512;
    for (int c = 0; c < 512; c++) acc = fmaf(pl[c], w[c], acc);
    h1[t] = fmaxf(acc, 0.0f);
  }
  __syncthreads();
  for (int c = t; c < 512; c += 256){
    float acc = bse2[c];
    const float* w = Wse2 + c * 32;
    #pragma unroll
    for (int j = 0; j < 32; j++) acc = fmaf(h1[j], w[j], acc);
    cw[b * 512 + c] = 1.0f / (1.0f + expf(-acc));
  }
}

// ------------------------------------------------------------------
// 4+6 fused) k_spxf: one pass over x producing mbuf (f32) + xfB (bf16^T)
// ------------------------------------------------------------------
__global__ __launch_bounds__(256) void k_spxf(const float* __restrict__ x,
    const float* __restrict__ Wsp, const float* __restrict__ bsp,
    const float* __restrict__ cw, float* __restrict__ mbuf, u16* __restrict__ xfB){
  __shared__ float wsh[4096];
  __shared__ float cwl[512];
  __shared__ float tile[64][36];
  __shared__ float part[8][256];
  int t = threadIdx.x;
  int b = blockIdx.x >> 5, n0 = (blockIdx.x & 31) << 5;
  for (int i = t; i < 4096; i += 256) wsh[i] = Wsp[i];
  cwl[t] = cw[b * 512 + t];
  cwl[t + 256] = cw[b * 512 + t + 256];

  int nl = t & 31, cg = t >> 5;
  int lr = t >> 2, lc = (t & 3) << 3;
  float acc[8] = {0,0,0,0,0,0,0,0};

  for (int cb = 0; cb < 8; cb++){
    __syncthreads();
    const float* xp = x + ((size_t)(b * 512 + cb * 64 + lr) << 10) + n0 + lc;
    float4 v0 = *(const float4*)xp;
    float4 v1 = *(const float4*)(xp + 4);
    *(float4*)&tile[lr][lc]     = v0;
    *(float4*)&tile[lr][lc + 4] = v1;
    __syncthreads();
    float sc[8];
    #pragma unroll
    for (int i = 0; i < 8; i++){
      int c = cb * 64 + cg * 8 + i;
      float v = tile[cg * 8 + i][nl];
      sc[i] = v * cwl[c];
      #pragma unroll
      for (int h = 0; h < 8; h++) acc[h] = fmaf(v, wsh[(h << 9) + c], acc[h]);
    }
    union { u32 d[4]; us8 v; } xu;
    #pragma unroll
    for (int i = 0; i < 4; i++) xu.d[i] = cvtpk(sc[2*i], sc[2*i+1]);
    *(us8*)&xfB[(((size_t)(b * 1024 + n0 + nl)) << 9) + cb * 64 + cg * 8] = xu.v;
  }
  #pragma unroll
  for (int h = 0; h < 8; h++) part[cg][h * 32 + nl] = acc[h];
  __syncthreads();
  {
    int h = t >> 5, px = t & 31;
    float s = bsp[h];
    #pragma unroll
    for (int g2 = 0; g2 < 8; g2++) s += part[g2][h * 32 + px];
    mbuf[(((size_t)(b * 8 + h)) << 10) + n0 + px] = 1.0f / (1.0f + expf(-s));
  }
}

// ------------------------------------------------------------------
// 5) adaptive pool 7x7, threshold, upsample -> bneg (B,8,N) in {0, NEGS}
// ------------------------------------------------------------------
__global__ void k_mask(const float* __restrict__ mbuf, float* __restrict__ bneg){
  __shared__ float sm[1024];
  __shared__ float mg[49];
  int bh = blockIdx.x, t = threadIdx.x;
  const float* mp = mbuf + ((size_t)bh << 10);
  for (int i = t; i < 1024; i += 64) sm[i] = mp[i];
  __syncthreads();
  if (t < 49){
    int ci = t / 7, cj = t % 7;
    int r0 = (ci * 32) / 7, r1 = ((ci + 1) * 32 + 6) / 7;
    int c0 = (cj * 32) / 7, c1 = ((cj + 1) * 32 + 6) / 7;
    float acc = 0.0f;
    for (int cc = c0; cc < c1; cc++){
      float rs = 0.0f;
      for (int rr = r0; rr < r1; rr++) rs += sm[rr * 32 + cc];
      acc += rs / (float)(r1 - r0);
    }
    float v = acc / (float)(c1 - c0);
    mg[t] = (v > 0.5f) ? 1.0f : 0.0f;
  }
  __syncthreads();
  for (int i = t; i < 1024; i += 64){
    int r = i >> 5, c = i & 31;
    float m = mg[((r * 7) >> 5) * 7 + ((c * 7) >> 5)];
    bneg[((size_t)bh << 10) + i] = (m > 0.5f) ? 0.0f : NEGS;
  }
}

// ------------------------------------------------------------------
// 7/9) bf16 MFMA GEMM — 3-slot distance-2 pipeline, counted vmcnt(4),
//   raw s_barrier (no vmcnt-0 drain in loop — T4). global_load_lds(16B).
//   LDS 48KB; occupancy still VGPR-limited at 3 blocks/CU (free).
// ------------------------------------------------------------------
template<int MODE>
DI void gemm_body(const u16* __restrict__ A, const u16* __restrict__ Bw,
    const float* __restrict__ b0, const float* __restrict__ b1, const float* __restrict__ b2,
    u16* __restrict__ outQ, u16* __restrict__ outK, u16* __restrict__ outV, u16* __restrict__ outO){
  __shared__ __align__(16) u16 smem[24576];   // 3 slots x (A 8KB + B 8KB)
  int m0 = blockIdx.x * 128, n0 = blockIdx.y * 128;
  bool vblk = (MODE == 0) && (n0 >= 1024);
  int t = threadIdx.x, lane = t & 63, w = t >> 6;
  int wr = w >> 1, wc = w & 1;
  int g = lane >> 4, li = lane & 15;
  f32x4 acc[4][4];
  #pragma unroll
  for (int mt = 0; mt < 4; mt++)
    #pragma unroll
    for (int nt = 0; nt < 4; nt++) acc[mt][nt] = (f32x4){0.f, 0.f, 0.f, 0.f};

  int cof = (((lane & 3) ^ ((lane >> 3) & 3)) << 3);
  int rl = lane >> 2;
  const u16* gA = A  + (size_t)(m0 + w * 32 + rl) * 512 + cof;
  const u16* gB = Bw + (size_t)(n0 + w * 32 + rl) * 512 + cof;
  u16* lA = smem + (w * 32) * 32;          // + slot*8192
  u16* lB = smem + 4096 + (w * 32) * 32;

  // each STAGE = exactly 4 vmem instructions per wave (vmcnt arithmetic)
  #define STAGE(slot, k0)                                             \
    gload16(gA + (k0),            lA + (slot) * 8192);                \
    gload16(gA + (k0) + 16 * 512, lA + (slot) * 8192 + 512);          \
    gload16(gB + (k0),            lB + (slot) * 8192);                \
    gload16(gB + (k0) + 16 * 512, lB + (slot) * 8192 + 512);

  STAGE(0, 0);
  STAGE(1, 32);

  int rsw = ((li >> 1) & 3);
  int cA = (g ^ rsw) << 3;
  #pragma unroll 4
  for (int ks = 0; ks < 16; ks++){
    // wait for slot ks's 4 loads (issued 2 iters ago); keep next stage in flight
    if (ks < 15) asm volatile("s_waitcnt vmcnt(4)" ::: "memory");
    else         asm volatile("s_waitcnt vmcnt(0)" ::: "memory");
    __builtin_amdgcn_sched_barrier(0);
    __builtin_amdgcn_s_barrier();          // raw: no compiler vmcnt(0) drain
    __builtin_amdgcn_sched_barrier(0);
    if (ks <= 13){ STAGE((ks + 2) % 3, (ks + 2) * 32); }
    const u16* Ac = smem + (ks % 3) * 8192;
    const u16* Bc = smem + (ks % 3) * 8192 + 4096;
    bf16x8 afr[4], bfr[4];
    #pragma unroll
    for (int mt = 0; mt < 4; mt++)
      afr[mt] = *(const bf16x8*)&Ac[(wr * 64 + mt * 16 + li) * 32 + cA];
    #pragma unroll
    for (int nt = 0; nt < 4; nt++)
      bfr[nt] = *(const bf16x8*)&Bc[(wc * 64 + nt * 16 + li) * 32 + cA];
    if (vblk){
      #pragma unroll
      for (int mt = 0; mt < 4; mt++)
        #pragma unroll
        for (int nt = 0; nt < 4; nt++)
          acc[mt][nt] = __builtin_amdgcn_mfma_f32_16x16x32_bf16(afr[mt], bfr[nt], acc[mt][nt], 0, 0, 0);
    } else {
      #pragma unroll
      for (int mt = 0; mt < 4; mt++)
        #pragma unroll
        for (int nt = 0; nt < 4; nt++)
          acc[mt][nt] = __builtin_amdgcn_mfma_f32_16x16x32_bf16(bfr[nt], afr[mt], acc[mt][nt], 0, 0, 0);
    }
  }
  #undef STAGE

  // ---- two-pass LDS-staged coalesced epilogue (first __syncthreads
  //      guarantees all waves done reading before Cl overlays smem)
  u16* Cl = smem;   // 64 x 136
  const float* bb = vblk ? b2 : ((MODE == 0 && (n0 >> 9)) ? b1 : b0);
  #pragma unroll
  for (int p = 0; p < 2; p++){
    __syncthreads();
    if (vblk){
      if (wc == p){
        #pragma unroll
        for (int mt = 0; mt < 4; mt++){
          #pragma unroll
          for (int nt = 0; nt < 4; nt++){
            int row = nt * 16 + li;
            float bias = bb[(n0 & 511) + p * 64 + row];
            int col = wr * 64 + ((mt >> 1) << 5) + (g << 3) + ((mt & 1) << 2);
            union { u32 d[2]; us4 v; } pu;
            pu.d[0] = cvtpk(acc[mt][nt][0] + bias, acc[mt][nt][1] + bias);
            pu.d[1] = cvtpk(acc[mt][nt][2] + bias, acc[mt][nt][3] + bias);
            *(us4*)&Cl[row * 136 + col] = pu.v;
          }
        }
      }
    } else {
      if (wr == p){
        #pragma unroll
        for (int mt = 0; mt < 4; mt++){
          #pragma unroll
          for (int nt = 0; nt < 4; nt++){
            int row = mt * 16 + li;
            int ob = wc * 64 + nt * 16 + (g << 2);
            float4 bias4 = *(const float4*)&bb[(n0 & 511) + ob];
            union { u32 d[2]; us4 v; } pu;
            pu.d[0] = cvtpk(acc[mt][nt][0] + bias4.x, acc[mt][nt][1] + bias4.y);
            pu.d[1] = cvtpk(acc[mt][nt][2] + bias4.z, acc[mt][nt][3] + bias4.w);
            *(us4*)&Cl[row * 136 + ob] = pu.v;
          }
        }
      }
    }
    __syncthreads();
    int r = t >> 4, ol = (t & 15) << 3;
    if (vblk){
      int b = m0 >> 10, nt0 = m0 & 1023;
      #pragma unroll
      for (int pp = 0; pp < 4; pp++){
        int rr = pp * 16 + r;
        int c = (n0 & 511) + p * 64 + rr, h = c >> 6, dv = c & 63;
        us8 v = *(us8*)&Cl[rr * 136 + ol];
        *(us8*)&outV[(((size_t)(b * 8 + h)) << 16) + ((size_t)dv << 10) + nt0 + ol] = v;
      }
    } else if (MODE == 0){
      u16* base = (n0 >> 9) ? outK : outQ;
      #pragma unroll
      for (int pp = 0; pp < 4; pp++){
        int rr = pp * 16 + r;
        int m = m0 + p * 64 + rr, b = m >> 10, n = m & 1023;
        int c = (n0 & 511) + ol, h = c >> 6, dv = c & 63;
        us8 v = *(us8*)&Cl[rr * 136 + ol];
        *(us8*)&base[(((size_t)(b * 8 + h)) << 16) + ((size_t)n << 6) + dv] = v;
      }
    } else {
      #pragma unroll
      for (int pp = 0; pp < 4; pp++){
        int rr = pp * 16 + r;
        int m = m0 + p * 64 + rr;
        us8 v = *(us8*)&Cl[rr * 136 + ol];
        *(us8*)&outO[((size_t)m << 9) + n0 + ol] = v;
      }
    }
  }
}

__global__ __launch_bounds__(256) void k_gemm_qkv(const u16* __restrict__ A, const u16* __restrict__ Bw,
    const float* __restrict__ b0, const float* __restrict__ b1, const float* __restrict__ b2,
    u16* __restrict__ outQ, u16* __restrict__ outK, u16* __restrict__ outV){
  gemm_body<0>(A, Bw, b0, b1, b2, outQ, outK, outV, nullptr);
}

__global__ __launch_bounds__(256) void k_gemm_o(const u16* __restrict__ A, const u16* __restrict__ Bw,
    const float* __restrict__ b0, u16* __restrict__ outO){
  gemm_body<1>(A, Bw, b0, nullptr, nullptr, nullptr, nullptr, nullptr, outO);
}

// ------------------------------------------------------------------
// 8) flash attention: 32 q-rows/wave, pitch-88 LDS, dbuf, base-2 softmax,
//    cvt_pk, defer-max, XCD swizzle, setprio. (proven r11/r13 structure)
// ------------------------------------------------------------------
__global__ __launch_bounds__(256) void k_flash(const u16* __restrict__ Q, const u16* __restrict__ K,
    const u16* __restrict__ Vt, const float* __restrict__ bneg, u16* __restrict__ attnB){
  __shared__ __align__(16) u16 Ks[2][64 * 88];
  __shared__ __align__(16) u16 Vts[2][64 * 88];
  __shared__ float mks[2][64];
  int hw = blockIdx.x;
  int bid = ((hw & 7) << 6) + (hw >> 3);
  int bh = bid >> 3, q0 = (bid & 7) << 7;
  int t = threadIdx.x, lane = t & 63, w = t >> 6;
  int g = lane >> 4, li = lane & 15;

  const u16* Kp = K  + ((size_t)bh << 16);
  const u16* Vp = Vt + ((size_t)bh << 16);
  const float* bp = bneg + ((size_t)bh << 10);

  bf16x8 qf0a, qf1a, qf0b, qf1b;
  {
    const u16* qra = Q + ((size_t)bh << 16) + ((size_t)(q0 + w * 32 + li) << 6);
    qf0a = *(const bf16x8*)(qra + g * 8);
    qf1a = *(const bf16x8*)(qra + 32 + g * 8);
    const u16* qrb = qra + (16 << 6);
    qf0b = *(const bf16x8*)(qrb + g * 8);
    qf1b = *(const bf16x8*)(qrb + 32 + g * 8);
  }
  float bnqa = bp[q0 + w * 32 + li];
  float bnqb = bp[q0 + w * 32 + 16 + li];

  f32x4 oaccA[4], oaccB[4];
  #pragma unroll
  for (int dt = 0; dt < 4; dt++){
    oaccA[dt] = (f32x4){0.f, 0.f, 0.f, 0.f};
    oaccB[dt] = (f32x4){0.f, 0.f, 0.f, 0.f};
  }
  float mrunA = -INFINITY, lrunA = 0.0f, mrunB = -INFINITY, lrunB = 0.0f;

  int sr = t >> 2, sc = (t & 3) << 4;
  const u16* kg = Kp + ((size_t)sr << 6) + sc;
  const u16* vg = Vp + ((size_t)sr << 10) + sc;
  uint4 kr0 = *(const uint4*)(kg), kr1 = *(const uint4*)(kg + 8);
  uint4 vr0 = *(const uint4*)(vg), vr1 = *(const uint4*)(vg + 8);
  float mr = (t < 64) ? bp[t] : 0.0f;

  *(uint4*)&Ks[0][sr * 88 + sc]      = kr0;
  *(uint4*)&Ks[0][sr * 88 + sc + 8]  = kr1;
  *(uint4*)&Vts[0][sr * 88 + sc]     = vr0;
  *(uint4*)&Vts[0][sr * 88 + sc + 8] = vr1;
  if (t < 64) mks[0][t] = mr;
  __syncthreads();

  for (int kt = 0; kt < 16; kt++){
    int buf = kt & 1;
    if (kt < 15){
      kr0 = *(const uint4*)(kg + (kt + 1) * 4096);
      kr1 = *(const uint4*)(kg + (kt + 1) * 4096 + 8);
      vr0 = *(const uint4*)(vg + (kt + 1) * 64);
      vr1 = *(const uint4*)(vg + (kt + 1) * 64 + 8);
      if (t < 64) mr = bp[(kt + 1) * 64 + t];
    }

    f32x4 sa[4], sb[4];
    #pragma unroll
    for (int mt = 0; mt < 4; mt++){ sa[mt] = (f32x4){0.f,0.f,0.f,0.f}; sb[mt] = (f32x4){0.f,0.f,0.f,0.f}; }
    __builtin_amdgcn_s_setprio(1);
    #pragma unroll
    for (int mt = 0; mt < 4; mt++){
      bf16x8 kf0 = *(bf16x8*)&Ks[buf][(mt * 16 + li) * 88 + g * 8];
      bf16x8 kf1 = *(bf16x8*)&Ks[buf][(mt * 16 + li) * 88 + 32 + g * 8];
      sa[mt] = __builtin_amdgcn_mfma_f32_16x16x32_bf16(kf0, qf0a, sa[mt], 0, 0, 0);
      sa[mt] = __builtin_amdgcn_mfma_f32_16x16x32_bf16(kf1, qf1a, sa[mt], 0, 0, 0);
      sb[mt] = __builtin_amdgcn_mfma_f32_16x16x32_bf16(kf0, qf0b, sb[mt], 0, 0, 0);
      sb[mt] = __builtin_amdgcn_mfma_f32_16x16x32_bf16(kf1, qf1b, sb[mt], 0, 0, 0);
    }
    __builtin_amdgcn_s_setprio(0);

    union { u32 d[4]; bf16x8 v; } u0a, u1a, u0b, u1b;
    {
      float tm[4];
      #pragma unroll
      for (int mt = 0; mt < 4; mt++){
        float4 bk = *(const float4*)&mks[buf][mt * 16 + g * 4];
        float s0 = fmaf(sa[mt][0], QKSCL, fminf(bk.x, bnqa));
        float s1 = fmaf(sa[mt][1], QKSCL, fminf(bk.y, bnqa));
        float s2 = fmaf(sa[mt][2], QKSCL, fminf(bk.z, bnqa));
        float s3 = fmaf(sa[mt][3], QKSCL, fminf(bk.w, bnqa));
        sa[mt][0] = s0; sa[mt][1] = s1; sa[mt][2] = s2; sa[mt][3] = s3;
        tm[mt] = fmaxf(fmaxf(s0, s1), fmaxf(s2, s3));
      }
      float tmax = fmaxf(fmaxf(tm[0], tm[1]), fmaxf(tm[2], tm[3]));
      tmax = fmaxf(tmax, __shfl_xor(tmax, 16, 64));
      tmax = fmaxf(tmax, __shfl_xor(tmax, 32, 64));
      if (!__all(tmax <= mrunA + DEFTH)){
        float mnew = fmaxf(mrunA, tmax);
        float scl = exp2a(mrunA - mnew);
        mrunA = mnew; lrunA *= scl;
        #pragma unroll
        for (int dt = 0; dt < 4; dt++)
          #pragma unroll
          for (int j = 0; j < 4; j++) oaccA[dt][j] *= scl;
      }
      float rs[4];
      #pragma unroll
      for (int mt = 0; mt < 4; mt++){
        float p0 = exp2a(sa[mt][0] - mrunA);
        float p1 = exp2a(sa[mt][1] - mrunA);
        float p2 = exp2a(sa[mt][2] - mrunA);
        float p3 = exp2a(sa[mt][3] - mrunA);
        sa[mt][0] = p0; sa[mt][1] = p1; sa[mt][2] = p2; sa[mt][3] = p3;
        rs[mt] = (p0 + p1) + (p2 + p3);
      }
      float rsum = (rs[0] + rs[1]) + (rs[2] + rs[3]);
      rsum += __shfl_xor(rsum, 16, 64);
      rsum += __shfl_xor(rsum, 32, 64);
      lrunA += rsum;
      u0a.d[0] = cvtpk(sa[0][0], sa[0][1]); u0a.d[1] = cvtpk(sa[0][2], sa[0][3]);
      u0a.d[2] = cvtpk(sa[1][0], sa[1][1]); u0a.d[3] = cvtpk(sa[1][2], sa[1][3]);
      u1a.d[0] = cvtpk(sa[2][0], sa[2][1]); u1a.d[1] = cvtpk(sa[2][2], sa[2][3]);
      u1a.d[2] = cvtpk(sa[3][0], sa[3][1]); u1a.d[3] = cvtpk(sa[3][2], sa[3][3]);
    }
    {
      float tm[4];
      #pragma unroll
      for (int mt = 0; mt < 4; mt++){
        float4 bk = *(const float4*)&mks[buf][mt * 16 + g * 4];
        float s0 = fmaf(sb[mt][0], QKSCL, fminf(bk.x, bnqb));
        float s1 = fmaf(sb[mt][1], QKSCL, fminf(bk.y, bnqb));
        float s2 = fmaf(sb[mt][2], QKSCL, fminf(bk.z, bnqb));
        float s3 = fmaf(sb[mt][3], QKSCL, fminf(bk.w, bnqb));
        sb[mt][0] = s0; sb[mt][1] = s1; sb[mt][2] = s2; sb[mt][3] = s3;
        tm[mt] = fmaxf(fmaxf(s0, s1), fmaxf(s2, s3));
      }
      float tmax = fmaxf(fmaxf(tm[0], tm[1]), fmaxf(tm[2], tm[3]));
      tmax = fmaxf(tmax, __shfl_xor(tmax, 16, 64));
      tmax = fmaxf(tmax, __shfl_xor(tmax, 32, 64));
      if (!__all(tmax <= mrunB + DEFTH)){
        float mnew = fmaxf(mrunB, tmax);
        float scl = exp2a(mrunB - mnew);
        mrunB = mnew; lrunB *= scl;
        #pragma unroll
        for (int dt = 0; dt < 4; dt++)
          #pragma unroll
          for (int j = 0; j < 4; j++) oaccB[dt][j] *= scl;
      }
      float rs[4];
      #pragma unroll
      for (int mt = 0; mt < 4; mt++){
        float p0 = exp2a(sb[mt][0] - mrunB);
        float p1 = exp2a(sb[mt][1] - mrunB);
        float p2 = exp2a(sb[mt][2] - mrunB);
        float p3 = exp2a(sb[mt][3] - mrunB);
        sb[mt][0] = p0; sb[mt][1] = p1; sb[mt][2] = p2; sb[mt][3] = p3;
        rs[mt] = (p0 + p1) + (p2 + p3);
      }
      float rsum = (rs[0] + rs[1]) + (rs[2] + rs[3]);
      rsum += __shfl_xor(rsum, 16, 64);
      rsum += __shfl_xor(rsum, 32, 64);
      lrunB += rsum;
      u0b.d[0] = cvtpk(sb[0][0], sb[0][1]); u0b.d[1] = cvtpk(sb[0][2], sb[0][3]);
      u0b.d[2] = cvtpk(sb[1][0], sb[1][1]); u0b.d[3] = cvtpk(sb[1][2], sb[1][3]);
      u1b.d[0] = cvtpk(sb[2][0], sb[2][1]); u1b.d[1] = cvtpk(sb[2][2], sb[2][3]);
      u1b.d[2] = cvtpk(sb[3][0], sb[3][1]); u1b.d[3] = cvtpk(sb[3][2], sb[3][3]);
    }

    __builtin_amdgcn_s_setprio(1);
    #pragma unroll
    for (int dt = 0; dt < 4; dt++){
      bf16x8 vf0 = *(bf16x8*)&Vts[buf][(dt * 16 + li) * 88 + g * 8];
      bf16x8 vf1 = *(bf16x8*)&Vts[buf][(dt * 16 + li) * 88 + 32 + g * 8];
      oaccA[dt] = __builtin_amdgcn_mfma_f32_16x16x32_bf16(vf0, u0a.v, oaccA[dt], 0, 0, 0);
      oaccA[dt] = __builtin_amdgcn_mfma_f32_16x16x32_bf16(vf1, u1a.v, oaccA[dt], 0, 0, 0);
      oaccB[dt] = __builtin_amdgcn_mfma_f32_16x16x32_bf16(vf0, u0b.v, oaccB[dt], 0, 0, 0);
      oaccB[dt] = __builtin_amdgcn_mfma_f32_16x16x32_bf16(vf1, u1b.v, oaccB[dt], 0, 0, 0);
    }
    __builtin_amdgcn_s_setprio(0);

    if (kt < 15){
      int nb = buf ^ 1;
      *(uint4*)&Ks[nb][sr * 88 + sc]      = kr0;
      *(uint4*)&Ks[nb][sr * 88 + sc + 8]  = kr1;
      *(uint4*)&Vts[nb][sr * 88 + sc]     = vr0;
      *(uint4*)&Vts[nb][sr * 88 + sc + 8] = vr1;
      if (t < 64) mks[nb][t] = mr;
      __syncthreads();
    }
  }

  int b = bh >> 3, h = bh & 7;
  float invA = 1.0f / lrunA, invB = 1.0f / lrunB;
  u16* opA = attnB + (((size_t)(b * 1024 + q0 + w * 32 + li)) << 9) + h * 64 + g * 4;
  u16* opB = opA + (16 << 9);
  #pragma unroll
  for (int dt = 0; dt < 4; dt++){
    union { u32 d[2]; us4 v; } oa, ob;
    oa.d[0] = cvtpk(oaccA[dt][0] * invA, oaccA[dt][1] * invA);
    oa.d[1] = cvtpk(oaccA[dt][2] * invA, oaccA[dt][3] * invA);
    ob.d[0] = cvtpk(oaccB[dt][0] * invB, oaccB[dt][1] * invB);
    ob.d[1] = cvtpk(oaccB[dt][2] * invB, oaccB[dt][3] * invB);
    *(us4*)(opA + dt * 16) = oa.v;
    *(us4*)(opB + dt * 16) = ob.v;
  }
}

// ------------------------------------------------------------------
// 10) LN over C + transpose to (B,C,N). 256 blocks x 32 tokens.
// ------------------------------------------------------------------
__global__ __launch_bounds__(256) void k_ln(const u16* __restrict__ xfB, const u16* __restrict__ attnO,
    const float* __restrict__ gamma, const float* __restrict__ beta, float* __restrict__ out){
  __shared__ float mu_s[32], rs_s[32];
  __shared__ float tile[32][65];
  int b = blockIdx.x >> 5, n0 = (blockIdx.x & 31) << 5;   // grid 256
  int t = threadIdx.x, w = t >> 6, lane = t & 63;

  for (int r = w * 8; r < w * 8 + 8; r++){
    size_t rb = ((size_t)(b * 1024 + n0 + r)) << 9;
    union { uint4 v; u16 u[8]; } av; av.v = *(const uint4*)(attnO + rb + lane * 8);
    union { uint4 v; u16 u[8]; } xv; xv.v = *(const uint4*)(xfB + rb + lane * 8);
    float s = 0.0f, s2 = 0.0f;
    #pragma unroll
    for (int i = 0; i < 8; i++){
      float v = b2f(av.u[i]) + b2f(xv.u[i]);
      s += v; s2 += v * v;
    }
    #pragma unroll
    for (int o = 32; o > 0; o >>= 1){ s += __shfl_xor(s, o, 64); s2 += __shfl_xor(s2, o, 64); }
    if (lane == 0){
      float mu = s * (1.0f / 512.0f);
      float var = s2 * (1.0f / 512.0f) - mu * mu;
      mu_s[r] = mu;
      rs_s[r] = 1.0f / sqrtf(var + 1e-5f);
    }
  }
  __syncthreads();

  for (int ch = 0; ch < 8; ch++){
    int c0 = ch * 64;
    {
      int r = t >> 3, cp = (t & 7) << 3;    // 32 rows x 8 chan-groups
      size_t rb = (((size_t)(b * 1024 + n0 + r)) << 9) + c0 + cp;
      float mu = mu_s[r], rstd = rs_s[r];
      union { uint4 v; u16 u[8]; } av; av.v = *(const uint4*)(attnO + rb);
      union { uint4 v; u16 u[8]; } xv; xv.v = *(const uint4*)(xfB + rb);
      #pragma unroll
      for (int i = 0; i < 8; i++){
        int c = c0 + cp + i;
        float v = b2f(av.u[i]) + b2f(xv.u[i]);
        tile[r][cp + i] = (v - mu) * rstd * gamma[c] + beta[c];
      }
    }
    __syncthreads();
    {
      int cl = t >> 2, np_ = (t & 3) << 3;  // 64 chans x 4 n-groups of 8
      float* op = out + (((size_t)(b * 512 + c0 + cl)) << 10) + n0 + np_;
      float4 v0 = { tile[np_ + 0][cl], tile[np_ + 1][cl], tile[np_ + 2][cl], tile[np_ + 3][cl] };
      float4 v1 = { tile[np_ + 4][cl], tile[np_ + 5][cl], tile[np_ + 6][cl], tile[np_ + 7][cl] };
      *(float4*)op = v0;
      *(float4*)(op + 4) = v1;
    }
    __syncthreads();
  }
}

// ------------------------------------------------------------------
extern "C" void kernel_launch(void* const* d_in, const int* in_sizes, int n_in,
                              void* d_out, int out_size, void* d_ws, size_t ws_size,
                              hipStream_t stream){
  (void)in_sizes; (void)n_in; (void)out_size; (void)ws_size;
  const float* x    = (const float*)d_in[0];
  const float* Wq   = (const float*)d_in[1];
  const float* bq   = (const float*)d_in[2];
  const float* Wk   = (const float*)d_in[3];
  const float* bk   = (const float*)d_in[4];
  const float* Wv   = (const float*)d_in[5];
  const float* bv   = (const float*)d_in[6];
  const float* Wo   = (const float*)d_in[7];
  const float* bo   = (const float*)d_in[8];
  const float* Wsp  = (const float*)d_in[9];
  const float* bsp  = (const float*)d_in[10];
  const float* Wse1 = (const float*)d_in[11];
  const float* bse1 = (const float*)d_in[12];
  const float* Wse2 = (const float*)d_in[13];
  const float* bse2 = (const float*)d_in[14];
  const float* gamma= (const float*)d_in[15];
  const float* beta = (const float*)d_in[16];
  float* out = (float*)d_out;

  char* ws = (char*)d_ws;
  size_t off = 0;
  auto alloc = [&](size_t bytes) -> void* {
    void* p = ws + off;
    off += (bytes + 255) & ~(size_t)255;
    return p;
  };
  u16*   WB     = (u16*)  alloc(1536 * 512 * 2);
  u16*   WoB    = (u16*)  alloc(512 * 512 * 2);
  float* pooled = (float*)alloc(4096 * 4);
  float* cw     = (float*)alloc(4096 * 4);
  float* mbuf   = (float*)alloc(65536 * 4);
  float* bneg   = (float*)alloc(65536 * 4);
  u16*   xfB    = (u16*)  alloc((size_t)8192 * 512 * 2);
  u16*   Qb     = (u16*)  alloc(8388608);
  u16*   Kb     = (u16*)  alloc(8388608);
  u16*   VtG    = (u16*)  alloc(8388608);
  u16*   attnB  = (u16*)  alloc(8388608);
  u16*   attnOb = Qb;   // alias Q (8.4MB) after flash

  k_prep  <<<dim3(2048), dim3(256), 0, stream>>>(Wq, Wk, Wv, Wo, WB, WoB, x, pooled);
  k_se    <<<dim3(8),    dim3(256), 0, stream>>>(pooled, Wse1, bse1, Wse2, bse2, cw);
  k_spxf  <<<dim3(256),  dim3(256), 0, stream>>>(x, Wsp, bsp, cw, mbuf, xfB);
  k_mask  <<<dim3(64),   dim3(64),  0, stream>>>(mbuf, bneg);
  k_gemm_qkv<<<dim3(64, 12), dim3(256), 0, stream>>>(xfB, WB, bq, bk, bv, Qb, Kb, VtG);
  k_flash <<<dim3(512),  dim3(256), 0, stream>>>(Qb, Kb, VtG, bneg, attnB);
  k_gemm_o<<<dim3(64, 4), dim3(256), 0, stream>>>(attnB, WoB, bo, attnOb);
  k_ln    <<<dim3(256),  dim3(256), 0, stream>>>(xfB, attnOb, gamma, beta, out);
}